// Round 1
// baseline (520.006 us; speedup 1.0000x reference)
//
#include <hip/hip_runtime.h>
#include <cstdint>
#include <cstddef>

// ---- problem constants ----
#define B_N     2
#define L_N     2048
#define DMODEL  512
#define DINNER  1024
#define DSTATE  64
#define NHEADS  16
#define HEADDIM 64
#define EPROJ   2192      // 2*DINNER + 2*DSTATE + NHEADS
#define OFF_Z   0
#define OFF_X   1024
#define OFF_B   2048
#define OFF_C   2112
#define OFF_DT  2176
#define LC      128       // scan chunk length
#define NC      (L_N / LC) // 16

__device__ __forceinline__ float silu_f(float v) { return v / (1.f + __expf(-v)); }

// =====================================================================
// Generic fp32 GEMM: C[M,N] = A[M,K] * Bt[N,K]^T   (both row-major)
// 64x64 block tile, 256 threads, 4x4 micro-tile, BK=16 LDS staging.
// M % 64 == 0 assumed; N guarded; K % 16 == 0 assumed.
// =====================================================================
__global__ __launch_bounds__(256) void gemm_bt_f32(
    const float* __restrict__ A, const float* __restrict__ Bt,
    float* __restrict__ C, int M, int N, int K)
{
    __shared__ float As[16][64];
    __shared__ float Bs[16][64];
    const int tid = threadIdx.x;
    const int bm = blockIdx.y * 64;
    const int bn = blockIdx.x * 64;
    const int tx = tid & 15;        // n-tile /4
    const int ty = tid >> 4;        // m-tile /4
    const int lr = tid >> 2;        // staging row 0..63
    const int lk = (tid & 3) * 4;   // staging k  {0,4,8,12}

    float acc[4][4] = {};

    for (int k0 = 0; k0 < K; k0 += 16) {
        float4 va = *(const float4*)(A + (size_t)(bm + lr) * K + k0 + lk);
        float4 vb = make_float4(0.f, 0.f, 0.f, 0.f);
        const int rn = bn + lr;
        if (rn < N) vb = *(const float4*)(Bt + (size_t)rn * K + k0 + lk);
        As[lk + 0][lr] = va.x; As[lk + 1][lr] = va.y;
        As[lk + 2][lr] = va.z; As[lk + 3][lr] = va.w;
        Bs[lk + 0][lr] = vb.x; Bs[lk + 1][lr] = vb.y;
        Bs[lk + 2][lr] = vb.z; Bs[lk + 3][lr] = vb.w;
        __syncthreads();
        #pragma unroll
        for (int k = 0; k < 16; ++k) {
            float4 a4 = *(const float4*)&As[k][ty * 4];
            float4 b4 = *(const float4*)&Bs[k][tx * 4];
            float a[4] = {a4.x, a4.y, a4.z, a4.w};
            float b[4] = {b4.x, b4.y, b4.z, b4.w};
            #pragma unroll
            for (int i = 0; i < 4; ++i)
                #pragma unroll
                for (int j = 0; j < 4; ++j)
                    acc[i][j] += a[i] * b[j];
        }
        __syncthreads();
    }

    #pragma unroll
    for (int i = 0; i < 4; ++i) {
        const int m = bm + ty * 4 + i;
        #pragma unroll
        for (int j = 0; j < 4; ++j) {
            const int n = bn + tx * 4 + j;
            if (n < N) C[(size_t)m * N + n] = acc[i][j];
        }
    }
}

// =====================================================================
// Depthwise causal conv (k=4, left pad 3) + bias + SiLU.
// xc[b,t,c] = silu(conv_b[c] + sum_k xs[b,t-3+k,c]*w[c,k]),  xs = proj[...,1024+c]
// =====================================================================
__global__ __launch_bounds__(256) void conv_silu_kern(
    const float* __restrict__ proj, const float* __restrict__ cw,
    const float* __restrict__ cb, float* __restrict__ xc)
{
    const int idx = blockIdx.x * 256 + threadIdx.x;   // over B*L*DINNER
    const int c = idx & (DINNER - 1);
    const int t = (idx >> 10) & (L_N - 1);
    const int b = idx >> 21;  // idx / (L_N*DINNER)

    float acc = cb[c];
    #pragma unroll
    for (int k = 0; k < 4; ++k) {
        const int tt = t - 3 + k;
        if (tt >= 0)
            acc += proj[((size_t)(b * L_N + tt)) * EPROJ + OFF_X + c] * cw[c * 4 + k];
    }
    xc[idx] = silu_f(acc);
}

// =====================================================================
// dA[b,t,h] = exp(softplus(dt + dt_bias[h]) * (-exp(A_log[h])))
// =====================================================================
__global__ __launch_bounds__(256) void da_kern(
    const float* __restrict__ proj, const float* __restrict__ A_log,
    const float* __restrict__ dt_bias, float* __restrict__ dAbuf)
{
    const int idx = blockIdx.x * 256 + threadIdx.x;   // over B*L*NHEADS
    const int h = idx & (NHEADS - 1);
    const int row = idx >> 4;                          // b*L + t
    float dt = proj[(size_t)row * EPROJ + OFF_DT + h] + dt_bias[h];
    float sp = (dt > 15.f) ? dt : log1pf(__expf(dt));
    float a = -__expf(A_log[h]);
    dAbuf[idx] = __expf(sp * a);
}

// =====================================================================
// Scan pass 1: per (b,h,chunk) local state from zero init + decay product.
// block = 256 threads: lane p = tid&63, quad q = tid>>6 owns n = q*16+i.
// =====================================================================
__global__ __launch_bounds__(256) void scan_pass1(
    const float* __restrict__ proj, const float* __restrict__ xc,
    const float* __restrict__ dAbuf, float* __restrict__ hl,
    float* __restrict__ Pc)
{
    const int bid = blockIdx.x;               // b*H*NC + h*NC + c
    const int c = bid & (NC - 1);
    const int h = (bid >> 4) & (NHEADS - 1);
    const int b = bid >> 8;
    const int tid = threadIdx.x;
    const int p = tid & 63;
    const int q = tid >> 6;

    __shared__ float sB[64];
    float hreg[16];
    #pragma unroll
    for (int i = 0; i < 16; ++i) hreg[i] = 0.f;
    float prod = 1.f;

    const int t0 = c * LC;
    for (int t = t0; t < t0 + LC; ++t) {
        const size_t row = (size_t)(b * L_N + t);
        if (tid < 64) sB[tid] = proj[row * EPROJ + OFF_B + tid];
        __syncthreads();
        const float xp = xc[row * DINNER + h * 64 + p];
        const float da = dAbuf[row * NHEADS + h];
        prod *= da;
        #pragma unroll
        for (int i = 0; i < 16; ++i)
            hreg[i] = da * hreg[i] + sB[q * 16 + i] * xp;
        __syncthreads();
    }

    float* outp = hl + (size_t)bid * (DSTATE * HEADDIM);
    #pragma unroll
    for (int i = 0; i < 16; ++i)
        outp[(q * 16 + i) * 64 + p] = hreg[i];
    if (tid == 0) Pc[bid] = prod;
}

// =====================================================================
// Scan pass 2: sequential over chunks, in-place h_local -> h_start.
// One block per (b,h); each thread owns 16 contiguous state entries.
// =====================================================================
__global__ __launch_bounds__(256) void scan_pass2(
    float* __restrict__ hl, const float* __restrict__ Pc)
{
    const int bid = blockIdx.x;           // b*H + h
    const int tid = threadIdx.x;
    float carry[16];
    #pragma unroll
    for (int i = 0; i < 16; ++i) carry[i] = 0.f;

    for (int c = 0; c < NC; ++c) {
        float* slot = hl + ((size_t)(bid * NC + c)) * (DSTATE * HEADDIM) + tid * 16;
        const float Pv = Pc[bid * NC + c];
        #pragma unroll
        for (int i = 0; i < 16; ++i) {
            const float tmp = slot[i];
            slot[i] = carry[i];
            carry[i] = Pv * carry[i] + tmp;
        }
    }
}

// =====================================================================
// Scan pass 3: true recurrence from h_start; y = C^T h; gate with silu(z);
// write y*silu(z) in-place over xc (block owns its (b,head,chunk) slice).
// =====================================================================
__global__ __launch_bounds__(256) void scan_pass3(
    const float* __restrict__ proj, float* __restrict__ xc,
    const float* __restrict__ dAbuf, const float* __restrict__ hl)
{
    const int bid = blockIdx.x;               // b*H*NC + h*NC + c
    const int c = bid & (NC - 1);
    const int h = (bid >> 4) & (NHEADS - 1);
    const int b = bid >> 8;
    const int tid = threadIdx.x;
    const int p = tid & 63;
    const int q = tid >> 6;

    __shared__ float sB[64];
    __shared__ float sC[64];
    __shared__ float red[4][64];

    float hreg[16];
    const float* hs = hl + (size_t)bid * (DSTATE * HEADDIM);
    #pragma unroll
    for (int i = 0; i < 16; ++i)
        hreg[i] = hs[(q * 16 + i) * 64 + p];

    const int t0 = c * LC;
    for (int t = t0; t < t0 + LC; ++t) {
        const size_t row = (size_t)(b * L_N + t);
        if (tid < 64) sB[tid] = proj[row * EPROJ + OFF_B + tid];
        else if (tid < 128) sC[tid - 64] = proj[row * EPROJ + OFF_C + (tid - 64)];
        __syncthreads();                       // (a) staging visible
        const float xp = xc[row * DINNER + h * 64 + p];
        const float da = dAbuf[row * NHEADS + h];
        float ypart = 0.f;
        #pragma unroll
        for (int i = 0; i < 16; ++i) {
            hreg[i] = da * hreg[i] + sB[q * 16 + i] * xp;
            ypart += sC[q * 16 + i] * hreg[i];
        }
        red[q][p] = ypart;
        __syncthreads();                       // (b) partials visible; xp reads done
        if (tid < 64) {
            const float y = red[0][p] + red[1][p] + red[2][p] + red[3][p];
            const float z = proj[row * EPROJ + OFF_Z + h * 64 + p];
            xc[row * DINNER + h * 64 + p] = y * silu_f(z);
        }
    }
}

// =====================================================================
extern "C" void kernel_launch(void* const* d_in, const int* in_sizes, int n_in,
                              void* d_out, int out_size, void* d_ws, size_t ws_size,
                              hipStream_t stream)
{
    const float* x       = (const float*)d_in[0];
    const float* W_in    = (const float*)d_in[1];
    const float* conv_w  = (const float*)d_in[2];
    const float* conv_b  = (const float*)d_in[3];
    const float* A_log   = (const float*)d_in[4];
    const float* dt_bias = (const float*)d_in[5];
    const float* W_out   = (const float*)d_in[6];
    float* out = (float*)d_out;

    // workspace layout (floats): ~61.3 MB total
    float* ws    = (float*)d_ws;
    float* proj  = ws;                                             // B*L*EPROJ   = 8,978,432
    float* xc    = proj  + (size_t)B_N * L_N * EPROJ;              // B*L*DINNER  = 4,194,304
    float* dAbuf = xc    + (size_t)B_N * L_N * DINNER;             // B*L*H       = 65,536
    float* hl    = dAbuf + (size_t)B_N * L_N * NHEADS;             // B*H*NC*4096 = 2,097,152
    float* Pc    = hl    + (size_t)B_N * NHEADS * NC * DSTATE * HEADDIM; // 512

    const int M = B_N * L_N;  // 4096

    // 1) in_proj: proj = x @ W_in^T   (M=4096, N=2192, K=512)
    gemm_bt_f32<<<dim3((EPROJ + 63) / 64, M / 64), 256, 0, stream>>>(
        x, W_in, proj, M, EPROJ, DMODEL);

    // 2) depthwise causal conv + silu -> xc
    conv_silu_kern<<<(B_N * L_N * DINNER) / 256, 256, 0, stream>>>(
        proj, conv_w, conv_b, xc);

    // 3) dA
    da_kern<<<(B_N * L_N * NHEADS) / 256, 256, 0, stream>>>(
        proj, A_log, dt_bias, dAbuf);

    // 4) chunked selective scan
    scan_pass1<<<B_N * NHEADS * NC, 256, 0, stream>>>(proj, xc, dAbuf, hl, Pc);
    scan_pass2<<<B_N * NHEADS, 256, 0, stream>>>(hl, Pc);
    scan_pass3<<<B_N * NHEADS * NC, 256, 0, stream>>>(proj, xc, dAbuf, hl);

    // 5) out_proj: out = (y*silu(z)) @ W_out^T   (M=4096, N=512, K=1024)
    gemm_bt_f32<<<dim3(DMODEL / 64, M / 64), 256, 0, stream>>>(
        xc, W_out, out, M, DMODEL, DINNER);
}

// Round 2
// 267.074 us; speedup vs baseline: 1.9470x; 1.9470x over previous
//
#include <hip/hip_runtime.h>
#include <cstdint>
#include <cstddef>

// ---- problem constants ----
#define B_N     2
#define L_N     2048
#define DMODEL  512
#define DINNER  1024
#define DSTATE  64
#define NHEADS  16
#define HEADDIM 64
#define EPROJ   2192      // 2*DINNER + 2*DSTATE + NHEADS
#define OFF_Z   0
#define OFF_X   1024
#define OFF_B   2048
#define OFF_C   2112
#define OFF_DT  2176
#define LC      64        // scan chunk length
#define NC      32        // L_N / LC

typedef unsigned short u16;
typedef __attribute__((ext_vector_type(8))) short short8;   // 8 bf16 (4 VGPRs)
typedef __attribute__((ext_vector_type(4))) float floatx4;  // MFMA acc

__device__ __forceinline__ float silu_f(float v) { return v / (1.f + __expf(-v)); }

__device__ __forceinline__ u16 f2bf(float f) {
    union { float f; uint32_t u; } v; v.f = f;
    uint32_t r = (v.u + 0x7FFFu + ((v.u >> 16) & 1u)) >> 16;  // RNE
    return (u16)r;
}

__device__ __forceinline__ float lane_bcast(float v, int n) {
    union { float f; uint32_t u; } a, b;
    a.f = v;
    b.u = __builtin_amdgcn_readlane(a.u, n);
    return b.f;
}

__device__ __forceinline__ void gload_lds16(const u16* g, u16* s) {
    __builtin_amdgcn_global_load_lds(
        (const __attribute__((address_space(1))) void*)g,
        (__attribute__((address_space(3))) void*)s,
        16, 0, 0);
}

// =====================================================================
// fp32 -> bf16 cast (vectorized x4)
// =====================================================================
__global__ __launch_bounds__(256) void cast_bf16_kern(
    const float* __restrict__ in, u16* __restrict__ out, int n4)
{
    const int i = blockIdx.x * 256 + threadIdx.x;
    if (i < n4) {
        float4 v = ((const float4*)in)[i];
        ushort4 o;
        o.x = f2bf(v.x); o.y = f2bf(v.y); o.z = f2bf(v.z); o.w = f2bf(v.w);
        ((ushort4*)out)[i] = o;
    }
}

// =====================================================================
// bf16 MFMA GEMM: C[M,N](f32) = A[M,K](bf16) * Bt[N,K](bf16)^T
// BM=128, BN in {128,64}, BK=32. 256 threads = 4 waves (2x2 wave grid),
// each wave 64 x BN/2 via 4 x (BN/32) mfma_f32_16x16x32_bf16 tiles.
// global_load_lds width-16 staging (m97 pattern). M%128==0, K%32==0.
// =====================================================================
template<int BN, bool GUARD>
__global__ __launch_bounds__(256) void gemm_mfma_bt(
    const u16* __restrict__ A, const u16* __restrict__ Bt,
    float* __restrict__ C, int M, int N, int K)
{
    constexpr int NI = BN / 32;
    __shared__ u16 As[128 * 32];
    __shared__ u16 Bs[BN * 32];

    const int tid = threadIdx.x;
    const int w   = tid >> 6;          // wave 0..3
    const int ln  = tid & 63;
    const int wm  = w >> 1, wn = w & 1;
    const int bm  = blockIdx.y * 128;
    const int bn  = blockIdx.x * BN;

    const int srow = ln >> 2;          // staging row within 16-row group
    const int skq  = (ln & 3) * 8;     // staging k offset (bf16 elems)

    const int fr = ln & 15;            // fragment row/col
    const int fq = (ln >> 4) * 8;      // fragment k offset

    floatx4 acc[4][NI];
    const floatx4 fzero = {0.f, 0.f, 0.f, 0.f};
    #pragma unroll
    for (int mi = 0; mi < 4; ++mi)
        #pragma unroll
        for (int ni = 0; ni < NI; ++ni) acc[mi][ni] = fzero;

    for (int k0 = 0; k0 < K; k0 += 32) {
        // stage A: 128 rows x 32 bf16
        #pragma unroll
        for (int r = 0; r < 2; ++r) {
            const int row = r * 64 + w * 16 + srow;
            gload_lds16(A + (size_t)(bm + row) * K + k0 + skq,
                        &As[(r * 64 + w * 16) * 32]);
        }
        // stage B: BN rows x 32 bf16 (row-clamped when GUARD)
        #pragma unroll
        for (int r = 0; r < BN / 64; ++r) {
            const int row = r * 64 + w * 16 + srow;
            int rn = bn + row;
            if (GUARD) rn = (rn < N) ? rn : (N - 1);
            gload_lds16(Bt + (size_t)rn * K + k0 + skq,
                        &Bs[(r * 64 + w * 16) * 32]);
        }
        __syncthreads();

        short8 af[4], bf[NI];
        #pragma unroll
        for (int mi = 0; mi < 4; ++mi)
            af[mi] = *(const short8*)&As[(wm * 64 + mi * 16 + fr) * 32 + fq];
        #pragma unroll
        for (int ni = 0; ni < NI; ++ni)
            bf[ni] = *(const short8*)&Bs[(wn * (BN / 2) + ni * 16 + fr) * 32 + fq];
        #pragma unroll
        for (int mi = 0; mi < 4; ++mi)
            #pragma unroll
            for (int ni = 0; ni < NI; ++ni)
                acc[mi][ni] = __builtin_amdgcn_mfma_f32_16x16x32_bf16(
                    af[mi], bf[ni], acc[mi][ni], 0, 0, 0);
        __syncthreads();
    }

    // store: D layout col=lane&15, row=(lane>>4)*4 + reg
    const int cr = (ln >> 4) * 4;
    const int cc = ln & 15;
    #pragma unroll
    for (int mi = 0; mi < 4; ++mi) {
        const int row0 = bm + wm * 64 + mi * 16 + cr;
        #pragma unroll
        for (int ni = 0; ni < NI; ++ni) {
            const int col = bn + wn * (BN / 2) + ni * 16 + cc;
            if (!GUARD || col < N) {
                #pragma unroll
                for (int r = 0; r < 4; ++r)
                    C[(size_t)(row0 + r) * N + col] = acc[mi][ni][r];
            }
        }
    }
}

// =====================================================================
// Depthwise causal conv (k=4, left pad 3) + bias + SiLU.
// =====================================================================
__global__ __launch_bounds__(256) void conv_silu_kern(
    const float* __restrict__ proj, const float* __restrict__ cw,
    const float* __restrict__ cb, float* __restrict__ xc)
{
    const int idx = blockIdx.x * 256 + threadIdx.x;   // over B*L*DINNER
    const int c = idx & (DINNER - 1);
    const int t = (idx >> 10) & (L_N - 1);
    const int b = idx >> 21;

    float acc = cb[c];
    #pragma unroll
    for (int k = 0; k < 4; ++k) {
        const int tt = t - 3 + k;
        if (tt >= 0)
            acc += proj[((size_t)(b * L_N + tt)) * EPROJ + OFF_X + c] * cw[c * 4 + k];
    }
    xc[idx] = silu_f(acc);
}

// =====================================================================
// dA[b,t,h] = exp(softplus(dt + dt_bias[h]) * (-exp(A_log[h])))
// =====================================================================
__global__ __launch_bounds__(256) void da_kern(
    const float* __restrict__ proj, const float* __restrict__ A_log,
    const float* __restrict__ dt_bias, float* __restrict__ dAbuf)
{
    const int idx = blockIdx.x * 256 + threadIdx.x;   // over B*L*NHEADS
    const int h = idx & (NHEADS - 1);
    const int row = idx >> 4;
    float dt = proj[(size_t)row * EPROJ + OFF_DT + h] + dt_bias[h];
    float sp = (dt > 15.f) ? dt : log1pf(__expf(dt));
    float a = -__expf(A_log[h]);
    dAbuf[idx] = __expf(sp * a);
}

// =====================================================================
// Scan pass 1: one wave per (b,h,chunk). lane = p, state h[n][p] in 64
// VGPRs. B broadcast via readlane. Zero LDS, zero barriers; prefetch x2.
// =====================================================================
__global__ __launch_bounds__(64) void scan_pass1(
    const float* __restrict__ proj, const float* __restrict__ xc,
    const float* __restrict__ dAbuf, float* __restrict__ hl,
    float* __restrict__ Pc)
{
    const int bid = blockIdx.x;               // ((b*H + h)*NC + c)
    const int c = bid & (NC - 1);
    const int h = (bid >> 5) & (NHEADS - 1);
    const int b = bid >> 9;
    const int ln = threadIdx.x;

    float hst[64];
    #pragma unroll
    for (int n = 0; n < 64; ++n) hst[n] = 0.f;
    float prod = 1.f;

    const size_t rmax = (size_t)B_N * L_N - 1;
    const size_t r0 = (size_t)b * L_N + c * LC;

    float B0 = proj[r0 * EPROJ + OFF_B + ln];
    float x0 = xc[r0 * DINNER + h * 64 + ln];
    float d0 = dAbuf[r0 * NHEADS + h];
    size_t r1 = (r0 + 1 < rmax) ? r0 + 1 : rmax;
    float B1 = proj[r1 * EPROJ + OFF_B + ln];
    float x1 = xc[r1 * DINNER + h * 64 + ln];
    float d1 = dAbuf[r1 * NHEADS + h];

    for (int tt = 0; tt < LC; tt += 2) {
        // step tt (consume buf0, prefetch tt+2 into buf0)
        {
            const float Bc = B0, xn = x0, da = d0;
            size_t rp = r0 + tt + 2; if (rp > rmax) rp = rmax;
            B0 = proj[rp * EPROJ + OFF_B + ln];
            x0 = xc[rp * DINNER + h * 64 + ln];
            d0 = dAbuf[rp * NHEADS + h];
            prod *= da;
            #pragma unroll
            for (int n = 0; n < 64; ++n)
                hst[n] = fmaf(da, hst[n], lane_bcast(Bc, n) * xn);
        }
        // step tt+1 (consume buf1, prefetch tt+3 into buf1)
        {
            const float Bc = B1, xn = x1, da = d1;
            size_t rp = r0 + tt + 3; if (rp > rmax) rp = rmax;
            B1 = proj[rp * EPROJ + OFF_B + ln];
            x1 = xc[rp * DINNER + h * 64 + ln];
            d1 = dAbuf[rp * NHEADS + h];
            prod *= da;
            #pragma unroll
            for (int n = 0; n < 64; ++n)
                hst[n] = fmaf(da, hst[n], lane_bcast(Bc, n) * xn);
        }
    }

    float* op = hl + (size_t)bid * (DSTATE * HEADDIM);
    #pragma unroll
    for (int n = 0; n < 64; ++n) op[n * 64 + ln] = hst[n];
    if (ln == 0) Pc[bid] = prod;
}

// =====================================================================
// Scan pass 2: sequential over NC chunks, in-place h_local -> h_start.
// =====================================================================
__global__ __launch_bounds__(256) void scan_pass2(
    float* __restrict__ hl, const float* __restrict__ Pc)
{
    const int bid = blockIdx.x;           // b*H + h
    const int tid = threadIdx.x;
    float carry[16];
    #pragma unroll
    for (int i = 0; i < 16; ++i) carry[i] = 0.f;

    for (int c = 0; c < NC; ++c) {
        float* slot = hl + ((size_t)(bid * NC + c)) * (DSTATE * HEADDIM) + tid * 16;
        const float Pv = Pc[bid * NC + c];
        #pragma unroll
        for (int i = 0; i < 16; ++i) {
            const float tmp = slot[i];
            slot[i] = carry[i];
            carry[i] = Pv * carry[i] + tmp;
        }
    }
}

// =====================================================================
// Scan pass 3: one wave per (b,h,chunk); recurrence from h_start;
// y_p = sum_n C_n h[n][p] complete per lane; gate + bf16 store.
// =====================================================================
__global__ __launch_bounds__(64) void scan_pass3(
    const float* __restrict__ proj, const float* __restrict__ xc,
    const float* __restrict__ dAbuf, const float* __restrict__ hl,
    u16* __restrict__ yz)
{
    const int bid = blockIdx.x;
    const int c = bid & (NC - 1);
    const int h = (bid >> 5) & (NHEADS - 1);
    const int b = bid >> 9;
    const int ln = threadIdx.x;

    float hst[64];
    const float* hs = hl + (size_t)bid * (DSTATE * HEADDIM);
    #pragma unroll
    for (int n = 0; n < 64; ++n) hst[n] = hs[n * 64 + ln];

    const size_t rmax = (size_t)B_N * L_N - 1;
    const size_t r0 = (size_t)b * L_N + c * LC;

    float B0 = proj[r0 * EPROJ + OFF_B + ln];
    float C0 = proj[r0 * EPROJ + OFF_C + ln];
    float z0 = proj[r0 * EPROJ + OFF_Z + h * 64 + ln];
    float x0 = xc[r0 * DINNER + h * 64 + ln];
    float d0 = dAbuf[r0 * NHEADS + h];
    size_t r1 = (r0 + 1 < rmax) ? r0 + 1 : rmax;
    float B1 = proj[r1 * EPROJ + OFF_B + ln];
    float C1 = proj[r1 * EPROJ + OFF_C + ln];
    float z1 = proj[r1 * EPROJ + OFF_Z + h * 64 + ln];
    float x1 = xc[r1 * DINNER + h * 64 + ln];
    float d1 = dAbuf[r1 * NHEADS + h];

    for (int tt = 0; tt < LC; tt += 2) {
        {
            const float Bc = B0, Cc = C0, zn = z0, xn = x0, da = d0;
            size_t rp = r0 + tt + 2; if (rp > rmax) rp = rmax;
            B0 = proj[rp * EPROJ + OFF_B + ln];
            C0 = proj[rp * EPROJ + OFF_C + ln];
            z0 = proj[rp * EPROJ + OFF_Z + h * 64 + ln];
            x0 = xc[rp * DINNER + h * 64 + ln];
            d0 = dAbuf[rp * NHEADS + h];
            float y = 0.f;
            #pragma unroll
            for (int n = 0; n < 64; ++n) {
                hst[n] = fmaf(da, hst[n], lane_bcast(Bc, n) * xn);
                y = fmaf(lane_bcast(Cc, n), hst[n], y);
            }
            const size_t row = r0 + tt;
            yz[row * DINNER + h * 64 + ln] = f2bf(y * silu_f(zn));
        }
        {
            const float Bc = B1, Cc = C1, zn = z1, xn = x1, da = d1;
            size_t rp = r0 + tt + 3; if (rp > rmax) rp = rmax;
            B1 = proj[rp * EPROJ + OFF_B + ln];
            C1 = proj[rp * EPROJ + OFF_C + ln];
            z1 = proj[rp * EPROJ + OFF_Z + h * 64 + ln];
            x1 = xc[rp * DINNER + h * 64 + ln];
            d1 = dAbuf[rp * NHEADS + h];
            float y = 0.f;
            #pragma unroll
            for (int n = 0; n < 64; ++n) {
                hst[n] = fmaf(da, hst[n], lane_bcast(Bc, n) * xn);
                y = fmaf(lane_bcast(Cc, n), hst[n], y);
            }
            const size_t row = r0 + tt + 1;
            yz[row * DINNER + h * 64 + ln] = f2bf(y * silu_f(zn));
        }
    }
}

// =====================================================================
extern "C" void kernel_launch(void* const* d_in, const int* in_sizes, int n_in,
                              void* d_out, int out_size, void* d_ws, size_t ws_size,
                              hipStream_t stream)
{
    const float* x       = (const float*)d_in[0];
    const float* W_in    = (const float*)d_in[1];
    const float* conv_w  = (const float*)d_in[2];
    const float* conv_b  = (const float*)d_in[3];
    const float* A_log   = (const float*)d_in[4];
    const float* dt_bias = (const float*)d_in[5];
    const float* W_out   = (const float*)d_in[6];
    float* out = (float*)d_out;

    // workspace layout: ~79 MB
    float* ws    = (float*)d_ws;
    float* proj  = ws;                                   // 4096*2192      f32
    float* xc    = proj  + (size_t)4096 * EPROJ;         // 4096*1024      f32
    float* dAbuf = xc    + (size_t)4096 * DINNER;        // 4096*16        f32
    float* hl    = dAbuf + (size_t)4096 * NHEADS;        // 1024*4096      f32
    float* Pc    = hl    + (size_t)B_N * NHEADS * NC * DSTATE * HEADDIM; // 1024
    u16*   ubase = (u16*)(Pc + 1024);
    u16*   xbf   = ubase;                                // 4096*512  bf16 (phase 1)
    u16*   wibf  = xbf + (size_t)4096 * DMODEL;          // 2192*512  bf16 (phase 1)
    u16*   yzbf  = ubase;                                // 4096*1024 bf16 (phase 2, reuses xbf)
    u16*   wobf  = yzbf + (size_t)4096 * DINNER;         // 512*1024  bf16 (phase 2)

    const int M = B_N * L_N;  // 4096

    // casts for in_proj
    cast_bf16_kern<<<(M * DMODEL / 4 + 255) / 256, 256, 0, stream>>>(x, xbf, M * DMODEL / 4);
    cast_bf16_kern<<<(EPROJ * DMODEL / 4 + 255) / 256, 256, 0, stream>>>(W_in, wibf, EPROJ * DMODEL / 4);

    // 1) in_proj: proj = x @ W_in^T  (M=4096, N=2192, K=512)
    gemm_mfma_bt<128, true><<<dim3((EPROJ + 127) / 128, M / 128), 256, 0, stream>>>(
        xbf, wibf, proj, M, EPROJ, DMODEL);

    // 2) depthwise causal conv + silu -> xc
    conv_silu_kern<<<(M * DINNER) / 256, 256, 0, stream>>>(proj, conv_w, conv_b, xc);

    // 3) dA
    da_kern<<<(M * NHEADS) / 256, 256, 0, stream>>>(proj, A_log, dt_bias, dAbuf);

    // 4) chunked selective scan (wave-autonomous, barrier-free passes)
    scan_pass1<<<B_N * NHEADS * NC, 64, 0, stream>>>(proj, xc, dAbuf, hl, Pc);
    scan_pass2<<<B_N * NHEADS, 256, 0, stream>>>(hl, Pc);
    scan_pass3<<<B_N * NHEADS * NC, 64, 0, stream>>>(proj, xc, dAbuf, hl, yzbf);

    // cast for out_proj
    cast_bf16_kern<<<(DMODEL * DINNER / 4 + 255) / 256, 256, 0, stream>>>(W_out, wobf, DMODEL * DINNER / 4);

    // 5) out_proj: out = yz @ W_out^T  (M=4096, N=512, K=1024)
    gemm_mfma_bt<64, false><<<dim3(DMODEL / 64, M / 128), 256, 0, stream>>>(
        yzbf, wobf, out, M, DMODEL, DINNER);
}

// Round 3
// 189.776 us; speedup vs baseline: 2.7401x; 1.4073x over previous
//
#include <hip/hip_runtime.h>
#include <cstdint>
#include <cstddef>

// ---- problem constants ----
#define B_N     2
#define L_N     2048
#define DMODEL  512
#define DINNER  1024
#define DSTATE  64
#define NHEADS  16
#define EPROJ   2192      // 2*DINNER + 2*DSTATE + NHEADS
#define OFF_Z   0
#define OFF_X   1024
#define OFF_B   2048
#define OFF_C   2112
#define OFF_DT  2176
#define LC      64        // scan chunk length (= matmul tile)
#define NC      32        // L_N / LC

typedef unsigned short u16;
typedef unsigned int   u32;
typedef __attribute__((ext_vector_type(8))) short short8;   // 8 bf16 (4 VGPRs)
typedef __attribute__((ext_vector_type(4))) float floatx4;  // MFMA acc

__device__ __forceinline__ float silu_f(float v) { return v / (1.f + __expf(-v)); }

__device__ __forceinline__ u16 f2bf(float f) {
    union { float f; uint32_t u; } v; v.f = f;
    uint32_t r = (v.u + 0x7FFFu + ((v.u >> 16) & 1u)) >> 16;  // RNE
    return (u16)r;
}

__device__ __forceinline__ u32 pack2(float lo, float hi) {
    return (u32)f2bf(lo) | ((u32)f2bf(hi) << 16);
}

__device__ __forceinline__ float lane_bcast(float v, int n) {
    union { float f; uint32_t u; } a, b;
    a.f = v;
    b.u = __builtin_amdgcn_readlane(a.u, n);
    return b.f;
}

// read bf16 fragment A[row][k0..k0+7] from pair-packed LDS tile (stride 33 dwords)
__device__ __forceinline__ short8 frag_ld(const u32* s, int row, int k0) {
    const u32* q = s + row * 33 + (k0 >> 1);
    union { u32 u[4]; short8 v; } r;
    r.u[0] = q[0]; r.u[1] = q[1]; r.u[2] = q[2]; r.u[3] = q[3];
    return r.v;
}

__device__ __forceinline__ void gload_lds16(const u16* g, u16* s) {
    __builtin_amdgcn_global_load_lds(
        (const __attribute__((address_space(1))) void*)g,
        (__attribute__((address_space(3))) void*)s,
        16, 0, 0);
}

// =====================================================================
// fused fp32 -> bf16 cast for x, W_in, W_out (one launch). n's in float4 quads.
// =====================================================================
__global__ __launch_bounds__(256) void cast3_kern(
    const float* __restrict__ s0, u16* __restrict__ d0, int n0,
    const float* __restrict__ s1, u16* __restrict__ d1, int n1,
    const float* __restrict__ s2, u16* __restrict__ d2, int n2)
{
    int i = blockIdx.x * 256 + threadIdx.x;
    const float* s; u16* d;
    if (i < n0)           { s = s0; d = d0; }
    else if (i < n0 + n1) { i -= n0; s = s1; d = d1; }
    else                  { i -= n0 + n1; if (i >= n2) return; s = s2; d = d2; }
    float4 v = ((const float4*)s)[i];
    ushort4 o;
    o.x = f2bf(v.x); o.y = f2bf(v.y); o.z = f2bf(v.z); o.w = f2bf(v.w);
    ((ushort4*)d)[i] = o;
}

// =====================================================================
// bf16 MFMA GEMM: C[M,N](f32) = A[M,K](bf16) * Bt[N,K](bf16)^T  (m97 pattern)
// =====================================================================
template<int BN, bool GUARD>
__global__ __launch_bounds__(256) void gemm_mfma_bt(
    const u16* __restrict__ A, const u16* __restrict__ Bt,
    float* __restrict__ C, int M, int N, int K)
{
    constexpr int NI = BN / 32;
    __shared__ u16 As[128 * 32];
    __shared__ u16 Bs[BN * 32];

    const int tid = threadIdx.x;
    const int w   = tid >> 6;
    const int ln  = tid & 63;
    const int wm  = w >> 1, wn = w & 1;
    const int bm  = blockIdx.y * 128;
    const int bn  = blockIdx.x * BN;

    const int srow = ln >> 2;
    const int skq  = (ln & 3) * 8;
    const int fr = ln & 15;
    const int fq = (ln >> 4) * 8;

    floatx4 acc[4][NI];
    const floatx4 fzero = {0.f, 0.f, 0.f, 0.f};
    #pragma unroll
    for (int mi = 0; mi < 4; ++mi)
        #pragma unroll
        for (int ni = 0; ni < NI; ++ni) acc[mi][ni] = fzero;

    for (int k0 = 0; k0 < K; k0 += 32) {
        #pragma unroll
        for (int r = 0; r < 2; ++r) {
            const int row = r * 64 + w * 16 + srow;
            gload_lds16(A + (size_t)(bm + row) * K + k0 + skq,
                        &As[(r * 64 + w * 16) * 32]);
        }
        #pragma unroll
        for (int r = 0; r < BN / 64; ++r) {
            const int row = r * 64 + w * 16 + srow;
            int rn = bn + row;
            if (GUARD) rn = (rn < N) ? rn : (N - 1);
            gload_lds16(Bt + (size_t)rn * K + k0 + skq,
                        &Bs[(r * 64 + w * 16) * 32]);
        }
        __syncthreads();

        short8 af[4], bf[NI];
        #pragma unroll
        for (int mi = 0; mi < 4; ++mi)
            af[mi] = *(const short8*)&As[(wm * 64 + mi * 16 + fr) * 32 + fq];
        #pragma unroll
        for (int ni = 0; ni < NI; ++ni)
            bf[ni] = *(const short8*)&Bs[(wn * (BN / 2) + ni * 16 + fr) * 32 + fq];
        #pragma unroll
        for (int mi = 0; mi < 4; ++mi)
            #pragma unroll
            for (int ni = 0; ni < NI; ++ni)
                acc[mi][ni] = __builtin_amdgcn_mfma_f32_16x16x32_bf16(
                    af[mi], bf[ni], acc[mi][ni], 0, 0, 0);
        __syncthreads();
    }

    const int cr = (ln >> 4) * 4;
    const int cc = ln & 15;
    #pragma unroll
    for (int mi = 0; mi < 4; ++mi) {
        const int row0 = bm + wm * 64 + mi * 16 + cr;
        #pragma unroll
        for (int ni = 0; ni < NI; ++ni) {
            const int col = bn + wn * (BN / 2) + ni * 16 + cc;
            if (!GUARD || col < N) {
                #pragma unroll
                for (int r = 0; r < 4; ++r)
                    C[(size_t)(row0 + r) * N + col] = acc[mi][ni][r];
            }
        }
    }
}

// =====================================================================
// Depthwise causal conv (k=4, left pad 3) + bias + SiLU -> bf16
// =====================================================================
__global__ __launch_bounds__(256) void conv_silu_kern(
    const float* __restrict__ proj, const float* __restrict__ cw,
    const float* __restrict__ cb, u16* __restrict__ xcb)
{
    const int idx = blockIdx.x * 256 + threadIdx.x;   // over B*L*DINNER
    const int c = idx & (DINNER - 1);
    const int t = (idx >> 10) & (L_N - 1);
    const int b = idx >> 21;

    float acc = cb[c];
    #pragma unroll
    for (int k = 0; k < 4; ++k) {
        const int tt = t - 3 + k;
        if (tt >= 0)
            acc += proj[((size_t)(b * L_N + tt)) * EPROJ + OFF_X + c] * cw[c * 4 + k];
    }
    xcb[idx] = f2bf(silu_f(acc));
}

// =====================================================================
// logdA[b,t,h] = softplus(dt + dt_bias[h]) * (-exp(A_log[h]))   (<= 0)
// =====================================================================
__global__ __launch_bounds__(256) void logda_kern(
    const float* __restrict__ proj, const float* __restrict__ A_log,
    const float* __restrict__ dt_bias, float* __restrict__ logda)
{
    const int idx = blockIdx.x * 256 + threadIdx.x;   // over B*L*NHEADS
    const int h = idx & (NHEADS - 1);
    const int row = idx >> 4;
    float dt = proj[(size_t)row * EPROJ + OFF_DT + h] + dt_bias[h];
    float sp = (dt > 15.f) ? dt : log1pf(__expf(dt));
    logda[idx] = sp * (-__expf(A_log[h]));
}

// =====================================================================
// SSD phase 1 (one wave per (b,h,chunk)):
//   La = cumsum(logdA);  Hc[n][p] = sum_s e^(La63-La_s) B[s][n] X[s][p]  (MFMA)
//   store Hc (f32), P=e^La63, La.
// =====================================================================
__global__ __launch_bounds__(64, 1) void ssd_phase1(
    const float* __restrict__ proj, const u16* __restrict__ xcb,
    const float* __restrict__ logda, float* __restrict__ hl,
    float* __restrict__ Pc, float* __restrict__ LaBuf)
{
    __shared__ u32 sBD[64 * 33];   // (e^(La63-La_s) B[s][n]) transposed: [n][s-pair]
    __shared__ u32 sXt[64 * 33];   // X^T: [p][s-pair]

    const int bid = blockIdx.x;               // ((b*16+h)*32 + c)
    const int c = bid & (NC - 1);
    const int h = (bid >> 5) & (NHEADS - 1);
    const int b = bid >> 9;
    const int ln = threadIdx.x;
    const int a = ln & 15, q = ln >> 4;
    const size_t r0 = (size_t)b * L_N + c * LC;

    // inclusive prefix sum of logdA over the chunk
    float La = logda[(r0 + ln) * NHEADS + h];
    #pragma unroll
    for (int d = 1; d < 64; d <<= 1) {
        float up = __shfl_up(La, d, 64);
        if (ln >= d) La += up;
    }
    LaBuf[(size_t)bid * 64 + ln] = La;
    const float La63 = lane_bcast(La, 63);

    // transpose-pack staging (2-way bank aliasing only)
    #pragma unroll 4
    for (int sp = 0; sp < 32; ++sp) {
        const int s = sp * 2;
        const float w0 = __expf(La63 - lane_bcast(La, s));
        const float w1 = __expf(La63 - lane_bcast(La, s + 1));
        const float b0 = proj[(r0 + s) * EPROJ + OFF_B + ln] * w0;
        const float b1 = proj[(r0 + s + 1) * EPROJ + OFF_B + ln] * w1;
        sBD[ln * 33 + sp] = pack2(b0, b1);
        const u32 x0 = xcb[(r0 + s) * DINNER + h * 64 + ln];
        const u32 x1 = xcb[(r0 + s + 1) * DINNER + h * 64 + ln];
        sXt[ln * 33 + sp] = x0 | (x1 << 16);
    }
    __syncthreads();

    short8 af[4][2], bf[4][2];
    #pragma unroll
    for (int t = 0; t < 4; ++t)
        #pragma unroll
        for (int ks = 0; ks < 2; ++ks) {
            af[t][ks] = frag_ld(sBD, t * 16 + a, ks * 32 + q * 8);
            bf[t][ks] = frag_ld(sXt, t * 16 + a, ks * 32 + q * 8);
        }
    floatx4 acc[4][4];
    const floatx4 fzero = {0.f, 0.f, 0.f, 0.f};
    #pragma unroll
    for (int tm = 0; tm < 4; ++tm)
        #pragma unroll
        for (int tn = 0; tn < 4; ++tn) acc[tm][tn] = fzero;
    #pragma unroll
    for (int tm = 0; tm < 4; ++tm)
        #pragma unroll
        for (int tn = 0; tn < 4; ++tn)
            #pragma unroll
            for (int ks = 0; ks < 2; ++ks)
                acc[tm][tn] = __builtin_amdgcn_mfma_f32_16x16x32_bf16(
                    af[tm][ks], bf[tn][ks], acc[tm][tn], 0, 0, 0);

    float* hp = hl + (size_t)bid * (DSTATE * 64);
    #pragma unroll
    for (int tm = 0; tm < 4; ++tm)
        #pragma unroll
        for (int tn = 0; tn < 4; ++tn)
            #pragma unroll
            for (int r = 0; r < 4; ++r)
                hp[(tm * 16 + q * 4 + r) * 64 + tn * 16 + a] = acc[tm][tn][r];
    if (ln == 0) Pc[bid] = __expf(La63);
}

// =====================================================================
// SSD phase 2: sequential carry over NC chunks; emits h_start^T (bf16 [p][n]).
// =====================================================================
__global__ __launch_bounds__(256) void ssd_phase2(
    const float* __restrict__ hl, const float* __restrict__ Pc,
    u16* __restrict__ hsT)
{
    const int bid = blockIdx.x;           // b*16 + h
    const int t = threadIdx.x;
    const int p = t & 63, q = t >> 6;     // thread owns n in [16q,16q+16)
    float carry[16];
    #pragma unroll
    for (int i = 0; i < 16; ++i) carry[i] = 0.f;

    for (int c = 0; c < NC; ++c) {
        const int slot = bid * NC + c;
        // write h_start (state entering chunk c) transposed, bf16
        u32 pk[8];
        #pragma unroll
        for (int j = 0; j < 8; ++j) pk[j] = pack2(carry[2 * j], carry[2 * j + 1]);
        uint4* dst = (uint4*)(hsT + ((size_t)slot * 64 + p) * 64 + q * 16);
        dst[0] = make_uint4(pk[0], pk[1], pk[2], pk[3]);
        dst[1] = make_uint4(pk[4], pk[5], pk[6], pk[7]);
        // carry = P*carry + Hc
        const float Pv = Pc[slot];
        const float* src = hl + (size_t)slot * 4096 + (q * 16) * 64 + p;
        #pragma unroll
        for (int i = 0; i < 16; ++i)
            carry[i] = Pv * carry[i] + src[i * 64];
    }
}

// =====================================================================
// SSD phase 3 (one wave per (b,h,chunk)):
//   S^T = B @ C  (MFMA);  W[i][s] = S[i,s] * e^(La_i-La_s) * (s<=i)
//   Y = diag(e^La) C @ h_start^T + W @ X^T   (chained MFMA)
//   yz = Y * silu(z)  (bf16)
// =====================================================================
__global__ __launch_bounds__(64, 1) void ssd_phase3(
    const float* __restrict__ proj, const u16* __restrict__ xcb,
    const u16* __restrict__ hsT, const float* __restrict__ LaBuf,
    u16* __restrict__ yz)
{
    __shared__ char lds[34048];
    u32* sBW   = (u32*)lds;              // B natural, then W (aliased)
    u32* sC    = (u32*)(lds + 8448);     // C natural [i][n-pair]
    u32* sXt   = (u32*)(lds + 16896);    // X^T [p][s-pair]
    u32* sH    = (u32*)(lds + 25344);    // h_start^T [p][n-pair]
    float* sLaF = (float*)(lds + 33792); // La[64]
    float* sY  = (float*)(lds + 8448);   // f32 [i][p] (64x66), aliases sC+sXt (epilogue only)

    const int bid = blockIdx.x;
    const int c = bid & (NC - 1);
    const int h = (bid >> 5) & (NHEADS - 1);
    const int b = bid >> 9;
    const int ln = threadIdx.x;
    const int a = ln & 15, q = ln >> 4;
    const int hw = ln >> 5, k32 = ln & 31;
    const size_t r0 = (size_t)b * L_N + c * LC;

    sLaF[ln] = LaBuf[(size_t)bid * 64 + ln];

    // stage B, C (natural, half-wave float2 row-pairs)
    #pragma unroll 4
    for (int rp = 0; rp < 32; ++rp) {
        const int row = rp * 2 + hw;
        const float2 vb = *(const float2*)(proj + (r0 + row) * EPROJ + OFF_B + 2 * k32);
        sBW[row * 33 + k32] = pack2(vb.x, vb.y);
        const float2 vc = *(const float2*)(proj + (r0 + row) * EPROJ + OFF_C + 2 * k32);
        sC[row * 33 + k32] = pack2(vc.x, vc.y);
    }
    // stage X^T (transpose-pack)
    #pragma unroll 4
    for (int sp = 0; sp < 32; ++sp) {
        const int s = sp * 2;
        const u32 x0 = xcb[(r0 + s) * DINNER + h * 64 + ln];
        const u32 x1 = xcb[(r0 + s + 1) * DINNER + h * 64 + ln];
        sXt[ln * 33 + sp] = x0 | (x1 << 16);
    }
    // stage h_start^T (already [p][n] in memory)
    const u32* hsrc = (const u32*)(hsT + (size_t)bid * 4096);
    #pragma unroll 4
    for (int rp = 0; rp < 32; ++rp) {
        const int row = rp * 2 + hw;
        sH[row * 33 + k32] = hsrc[row * 32 + k32];
    }
    __syncthreads();

    const floatx4 fzero = {0.f, 0.f, 0.f, 0.f};

    // ---- m1: S^T[s][i] = B @ C (tiles tm<=tn only) ----
    short8 bfr[4][2], cfr[4][2];
    #pragma unroll
    for (int t = 0; t < 4; ++t)
        #pragma unroll
        for (int ks = 0; ks < 2; ++ks) {
            bfr[t][ks] = frag_ld(sBW, t * 16 + a, ks * 32 + q * 8);
            cfr[t][ks] = frag_ld(sC,  t * 16 + a, ks * 32 + q * 8);
        }
    floatx4 accS[4][4];
    #pragma unroll
    for (int tm = 0; tm < 4; ++tm)
        #pragma unroll
        for (int tn = 0; tn < 4; ++tn) {
            if (tm > tn) continue;
            accS[tm][tn] = fzero;
            #pragma unroll
            for (int ks = 0; ks < 2; ++ks)
                accS[tm][tn] = __builtin_amdgcn_mfma_f32_16x16x32_bf16(
                    bfr[tm][ks], cfr[tn][ks], accS[tm][tn], 0, 0, 0);
        }
    __syncthreads();   // sBW (B) fully consumed; safe to overwrite with W

    // ---- build W[i][s] in sBW ----
    #pragma unroll
    for (int tn = 0; tn < 4; ++tn) {
        const int i = tn * 16 + a;
        const float Li = sLaF[i];
        #pragma unroll
        for (int tm = 0; tm < 4; ++tm) {
            const int d0 = i * 33 + tm * 8 + q * 2;
            if (tm > tn) {
                sBW[d0] = 0; sBW[d0 + 1] = 0;
            } else {
                const float4 Ls = *(const float4*)(sLaF + tm * 16 + q * 4);
                float v[4];
                #pragma unroll
                for (int r = 0; r < 4; ++r) {
                    const int s = tm * 16 + q * 4 + r;
                    const float w = (s <= i) ? __expf(Li - ((const float*)&Ls)[r]) : 0.f;
                    v[r] = accS[tm][tn][r] * w;
                }
                sBW[d0]     = pack2(v[0], v[1]);
                sBW[d0 + 1] = pack2(v[2], v[3]);
            }
        }
    }

    // ---- m4: accY = C @ h_start^T, then scale rows by e^La_i ----
    short8 hfr[4][2];
    #pragma unroll
    for (int t = 0; t < 4; ++t)
        #pragma unroll
        for (int ks = 0; ks < 2; ++ks)
            hfr[t][ks] = frag_ld(sH, t * 16 + a, ks * 32 + q * 8);
    floatx4 accY[4][4];
    #pragma unroll
    for (int ti = 0; ti < 4; ++ti)
        #pragma unroll
        for (int tp = 0; tp < 4; ++tp) {
            accY[ti][tp] = fzero;
            #pragma unroll
            for (int ks = 0; ks < 2; ++ks)
                accY[ti][tp] = __builtin_amdgcn_mfma_f32_16x16x32_bf16(
                    cfr[ti][ks], hfr[tp][ks], accY[ti][tp], 0, 0, 0);
        }
    #pragma unroll
    for (int ti = 0; ti < 4; ++ti) {
        const float4 Ls = *(const float4*)(sLaF + ti * 16 + q * 4);
        float e[4];
        #pragma unroll
        for (int r = 0; r < 4; ++r) e[r] = __expf(((const float*)&Ls)[r]);
        #pragma unroll
        for (int tp = 0; tp < 4; ++tp)
            #pragma unroll
            for (int r = 0; r < 4; ++r) accY[ti][tp][r] *= e[r];
    }
    __syncthreads();   // W writes visible (in-order anyway; belt & braces)

    // ---- m2: accY += W @ X^T ----
    short8 wfr[4][2], xfr[4][2];
    #pragma unroll
    for (int t = 0; t < 4; ++t)
        #pragma unroll
        for (int ks = 0; ks < 2; ++ks) {
            wfr[t][ks] = frag_ld(sBW, t * 16 + a, ks * 32 + q * 8);
            xfr[t][ks] = frag_ld(sXt, t * 16 + a, ks * 32 + q * 8);
        }
    #pragma unroll
    for (int ti = 0; ti < 4; ++ti)
        #pragma unroll
        for (int tp = 0; tp < 4; ++tp)
            #pragma unroll
            for (int ks = 0; ks < 2; ++ks)
                accY[ti][tp] = __builtin_amdgcn_mfma_f32_16x16x32_bf16(
                    wfr[ti][ks], xfr[tp][ks], accY[ti][tp], 0, 0, 0);
    __syncthreads();   // all frag reads done; sC/sXt region reusable as sY

    // ---- epilogue: LDS round-trip to row-contiguous, gate, store bf16 ----
    #pragma unroll
    for (int ti = 0; ti < 4; ++ti)
        #pragma unroll
        for (int tp = 0; tp < 4; ++tp)
            #pragma unroll
            for (int r = 0; r < 4; ++r)
                sY[(ti * 16 + q * 4 + r) * 66 + tp * 16 + a] = accY[ti][tp][r];
    __syncthreads();
    #pragma unroll 8
    for (int i = 0; i < 64; ++i) {
        const float y = sY[i * 66 + ln];
        const float z = proj[(r0 + i) * EPROJ + OFF_Z + h * 64 + ln];
        yz[(r0 + i) * DINNER + h * 64 + ln] = f2bf(y * silu_f(z));
    }
}

// =====================================================================
extern "C" void kernel_launch(void* const* d_in, const int* in_sizes, int n_in,
                              void* d_out, int out_size, void* d_ws, size_t ws_size,
                              hipStream_t stream)
{
    const float* x       = (const float*)d_in[0];
    const float* W_in    = (const float*)d_in[1];
    const float* conv_w  = (const float*)d_in[2];
    const float* conv_b  = (const float*)d_in[3];
    const float* A_log   = (const float*)d_in[4];
    const float* dt_bias = (const float*)d_in[5];
    const float* W_out   = (const float*)d_in[6];
    float* out = (float*)d_out;

    // workspace layout (~86 MB)
    float* ws    = (float*)d_ws;
    float* proj  = ws;                                          // 4096*2192 f32
    u16*   xcb   = (u16*)(proj + (size_t)4096 * EPROJ);         // 4096*1024 bf16
    float* logda = (float*)(xcb + (size_t)4096 * DINNER);       // 4096*16 f32
    float* hl    = logda + (size_t)4096 * NHEADS;               // 1024*4096 f32
    float* Pc    = hl + (size_t)1024 * 4096;                    // 1024
    float* LaBuf = Pc + 1024;                                   // 1024*64
    u16*   hsT   = (u16*)(LaBuf + 1024 * 64);                   // 1024*4096 bf16
    u16*   xbf   = hsT + (size_t)1024 * 4096;                   // 4096*512 bf16
    u16*   wibf  = xbf + (size_t)4096 * DMODEL;                 // 2192*512 bf16
    u16*   wobf  = wibf + (size_t)EPROJ * DMODEL;               // 512*1024 bf16
    u16*   yzbf  = wobf + (size_t)DMODEL * DINNER;              // 4096*1024 bf16

    const int M = B_N * L_N;  // 4096
    const int n0 = M * DMODEL / 4, n1 = EPROJ * DMODEL / 4, n2 = DMODEL * DINNER / 4;

    // 0) fused casts
    cast3_kern<<<(n0 + n1 + n2 + 255) / 256, 256, 0, stream>>>(
        x, xbf, n0, W_in, wibf, n1, W_out, wobf, n2);

    // 1) in_proj: proj = x @ W_in^T  (M=4096, N=2192, K=512)
    gemm_mfma_bt<128, true><<<dim3((EPROJ + 127) / 128, M / 128), 256, 0, stream>>>(
        xbf, wibf, proj, M, EPROJ, DMODEL);

    // 2) conv + silu -> bf16
    conv_silu_kern<<<(M * DINNER) / 256, 256, 0, stream>>>(proj, conv_w, conv_b, xcb);

    // 3) logdA
    logda_kern<<<(M * NHEADS) / 256, 256, 0, stream>>>(proj, A_log, dt_bias, logda);

    // 4) SSD chunked scan (MFMA)
    ssd_phase1<<<B_N * NHEADS * NC, 64, 0, stream>>>(proj, xcb, logda, hl, Pc, LaBuf);
    ssd_phase2<<<B_N * NHEADS, 256, 0, stream>>>(hl, Pc, hsT);
    ssd_phase3<<<B_N * NHEADS * NC, 64, 0, stream>>>(proj, xcb, hsT, LaBuf, yzbf);

    // 5) out_proj: out = yz @ W_out^T  (M=4096, N=512, K=1024)
    gemm_mfma_bt<64, false><<<dim3(DMODEL / 64, M / 128), 256, 0, stream>>>(
        yzbf, wobf, out, M, DMODEL, DINNER);
}

// Round 4
// 164.195 us; speedup vs baseline: 3.1670x; 1.1558x over previous
//
#include <hip/hip_runtime.h>
#include <cstdint>
#include <cstddef>

// ---- problem constants ----
#define B_N     2
#define L_N     2048
#define DMODEL  512
#define DINNER  1024
#define DSTATE  64
#define NHEADS  16
#define EPROJ   2192      // 2*DINNER + 2*DSTATE + NHEADS
#define OFF_Z   0
#define OFF_X   1024
#define OFF_B   2048
#define OFF_C   2112
#define OFF_DT  2176
#define LC      64        // scan chunk length (= matmul tile)
#define NC      32        // L_N / LC

typedef unsigned short u16;
typedef unsigned int   u32;
typedef __attribute__((ext_vector_type(8))) short short8;   // 8 bf16 (4 VGPRs)
typedef __attribute__((ext_vector_type(4))) float floatx4;  // MFMA acc

__device__ __forceinline__ float silu_f(float v) { return v / (1.f + __expf(-v)); }

__device__ __forceinline__ u16 f2bf(float f) {
    union { float f; uint32_t u; } v; v.f = f;
    uint32_t r = (v.u + 0x7FFFu + ((v.u >> 16) & 1u)) >> 16;  // RNE
    return (u16)r;
}

__device__ __forceinline__ u32 pack2(float lo, float hi) {
    return (u32)f2bf(lo) | ((u32)f2bf(hi) << 16);
}

__device__ __forceinline__ float lane_bcast(float v, int n) {
    union { float f; uint32_t u; } a, b;
    a.f = v;
    b.u = __builtin_amdgcn_readlane(a.u, n);
    return b.f;
}

// read bf16 fragment A[row][k0..k0+7] from pair-packed LDS tile (stride 33 dwords)
__device__ __forceinline__ short8 frag_ld(const u32* s, int row, int k0) {
    const u32* q = s + row * 33 + (k0 >> 1);
    union { u32 u[4]; short8 v; } r;
    r.u[0] = q[0]; r.u[1] = q[1]; r.u[2] = q[2]; r.u[3] = q[3];
    return r.v;
}

__device__ __forceinline__ void gload_lds16(const u16* g, u16* s) {
    __builtin_amdgcn_global_load_lds(
        (const __attribute__((address_space(1))) void*)g,
        (__attribute__((address_space(3))) void*)s,
        16, 0, 0);
}

// =====================================================================
// fused fp32 -> bf16 cast for x, W_in, W_out (one launch). n's in float4 quads.
// =====================================================================
__global__ __launch_bounds__(256) void cast3_kern(
    const float* __restrict__ s0, u16* __restrict__ d0, int n0,
    const float* __restrict__ s1, u16* __restrict__ d1, int n1,
    const float* __restrict__ s2, u16* __restrict__ d2, int n2)
{
    int i = blockIdx.x * 256 + threadIdx.x;
    const float* s; u16* d;
    if (i < n0)           { s = s0; d = d0; }
    else if (i < n0 + n1) { i -= n0; s = s1; d = d1; }
    else                  { i -= n0 + n1; if (i >= n2) return; s = s2; d = d2; }
    float4 v = ((const float4*)s)[i];
    ushort4 o;
    o.x = f2bf(v.x); o.y = f2bf(v.y); o.z = f2bf(v.z); o.w = f2bf(v.w);
    ((ushort4*)d)[i] = o;
}

// =====================================================================
// bf16 MFMA GEMM: C[M,N](f32) = A[M,K](bf16) * Bt[N,K](bf16)^T  (m97 pattern)
// =====================================================================
template<int BN, bool GUARD>
__global__ __launch_bounds__(256) void gemm_mfma_bt(
    const u16* __restrict__ A, const u16* __restrict__ Bt,
    float* __restrict__ C, int M, int N, int K)
{
    constexpr int NI = BN / 32;
    __shared__ u16 As[128 * 32];
    __shared__ u16 Bs[BN * 32];

    const int tid = threadIdx.x;
    const int w   = tid >> 6;
    const int ln  = tid & 63;
    const int wm  = w >> 1, wn = w & 1;
    const int bm  = blockIdx.y * 128;
    const int bn  = blockIdx.x * BN;

    const int srow = ln >> 2;
    const int skq  = (ln & 3) * 8;
    const int fr = ln & 15;
    const int fq = (ln >> 4) * 8;

    floatx4 acc[4][NI];
    const floatx4 fzero = {0.f, 0.f, 0.f, 0.f};
    #pragma unroll
    for (int mi = 0; mi < 4; ++mi)
        #pragma unroll
        for (int ni = 0; ni < NI; ++ni) acc[mi][ni] = fzero;

    for (int k0 = 0; k0 < K; k0 += 32) {
        #pragma unroll
        for (int r = 0; r < 2; ++r) {
            const int row = r * 64 + w * 16 + srow;
            gload_lds16(A + (size_t)(bm + row) * K + k0 + skq,
                        &As[(r * 64 + w * 16) * 32]);
        }
        #pragma unroll
        for (int r = 0; r < BN / 64; ++r) {
            const int row = r * 64 + w * 16 + srow;
            int rn = bn + row;
            if (GUARD) rn = (rn < N) ? rn : (N - 1);
            gload_lds16(Bt + (size_t)rn * K + k0 + skq,
                        &Bs[(r * 64 + w * 16) * 32]);
        }
        __syncthreads();

        short8 af[4], bf[NI];
        #pragma unroll
        for (int mi = 0; mi < 4; ++mi)
            af[mi] = *(const short8*)&As[(wm * 64 + mi * 16 + fr) * 32 + fq];
        #pragma unroll
        for (int ni = 0; ni < NI; ++ni)
            bf[ni] = *(const short8*)&Bs[(wn * (BN / 2) + ni * 16 + fr) * 32 + fq];
        #pragma unroll
        for (int mi = 0; mi < 4; ++mi)
            #pragma unroll
            for (int ni = 0; ni < NI; ++ni)
                acc[mi][ni] = __builtin_amdgcn_mfma_f32_16x16x32_bf16(
                    af[mi], bf[ni], acc[mi][ni], 0, 0, 0);
        __syncthreads();
    }

    const int cr = (ln >> 4) * 4;
    const int cc = ln & 15;
    #pragma unroll
    for (int mi = 0; mi < 4; ++mi) {
        const int row0 = bm + wm * 64 + mi * 16 + cr;
        #pragma unroll
        for (int ni = 0; ni < NI; ++ni) {
            const int col = bn + wn * (BN / 2) + ni * 16 + cc;
            if (!GUARD || col < N) {
                #pragma unroll
                for (int r = 0; r < 4; ++r)
                    C[(size_t)(row0 + r) * N + col] = acc[mi][ni][r];
            }
        }
    }
}

// =====================================================================
// Depthwise causal conv (k=4, left pad 3) + bias + SiLU -> bf16
// =====================================================================
__global__ __launch_bounds__(256) void conv_silu_kern(
    const float* __restrict__ proj, const float* __restrict__ cw,
    const float* __restrict__ cb, u16* __restrict__ xcb)
{
    const int idx = blockIdx.x * 256 + threadIdx.x;   // over B*L*DINNER
    const int c = idx & (DINNER - 1);
    const int t = (idx >> 10) & (L_N - 1);
    const int b = idx >> 21;

    float acc = cb[c];
    #pragma unroll
    for (int k = 0; k < 4; ++k) {
        const int tt = t - 3 + k;
        if (tt >= 0)
            acc += proj[((size_t)(b * L_N + tt)) * EPROJ + OFF_X + c] * cw[c * 4 + k];
    }
    xcb[idx] = f2bf(silu_f(acc));
}

// =====================================================================
// SSD phase 1 — 4-wave cooperative block per (b,h,chunk):
//   logdA computed in-kernel (per-wave redundant), La = cumsum,
//   Hc[n][p] = sum_s e^(La63-La_s) B[s][n] X[s][p]  (MFMA, wave w = tile-row w)
// =====================================================================
__global__ __launch_bounds__(256) void ssd_phase1(
    const float* __restrict__ proj, const u16* __restrict__ xcb,
    const float* __restrict__ A_log, const float* __restrict__ dt_bias,
    float* __restrict__ hl, float* __restrict__ Pc, float* __restrict__ LaBuf)
{
    __shared__ u32 sBD[64 * 33];   // (e^(La63-La_s) B[s][n])^T : [n][s-pair]
    __shared__ u32 sXt[64 * 33];   // X^T: [p][s-pair]

    const int bid = blockIdx.x;               // ((b*16+h)*32 + c)
    const int c = bid & (NC - 1);
    const int h = (bid >> 5) & (NHEADS - 1);
    const int b = bid >> 9;
    const int tid = threadIdx.x;
    const int w = tid >> 6, ln = tid & 63;
    const int a = ln & 15, q = ln >> 4;
    const size_t r0 = (size_t)b * L_N + c * LC;

    // logdA + inclusive cumsum (redundant per wave; all waves identical)
    float dt = proj[(r0 + ln) * EPROJ + OFF_DT + h] + dt_bias[h];
    float sp = (dt > 15.f) ? dt : log1pf(__expf(dt));
    float La = sp * (-__expf(A_log[h]));
    #pragma unroll
    for (int d = 1; d < 64; d <<= 1) {
        float up = __shfl_up(La, d, 64);
        if (ln >= d) La += up;
    }
    if (w == 0) LaBuf[(size_t)bid * 64 + ln] = La;
    const float La63 = lane_bcast(La, 63);

    // staging: wave w covers s-pairs [w*8, w*8+8)
    #pragma unroll
    for (int j = 0; j < 8; ++j) {
        const int sp_ = w * 8 + j, s = sp_ * 2;
        const float w0 = __expf(La63 - lane_bcast(La, s));
        const float w1 = __expf(La63 - lane_bcast(La, s + 1));
        const float b0 = proj[(r0 + s) * EPROJ + OFF_B + ln] * w0;
        const float b1 = proj[(r0 + s + 1) * EPROJ + OFF_B + ln] * w1;
        sBD[ln * 33 + sp_] = pack2(b0, b1);
        const u32 x0 = xcb[(r0 + s) * DINNER + h * 64 + ln];
        const u32 x1 = xcb[(r0 + s + 1) * DINNER + h * 64 + ln];
        sXt[ln * 33 + sp_] = x0 | (x1 << 16);
    }
    __syncthreads();

    // MFMA: wave w computes output tile-row tm=w (rows n in [16w,16w+16))
    short8 af[2], bf[4][2];
    #pragma unroll
    for (int ks = 0; ks < 2; ++ks)
        af[ks] = frag_ld(sBD, w * 16 + a, ks * 32 + q * 8);
    #pragma unroll
    for (int tn = 0; tn < 4; ++tn)
        #pragma unroll
        for (int ks = 0; ks < 2; ++ks)
            bf[tn][ks] = frag_ld(sXt, tn * 16 + a, ks * 32 + q * 8);

    const floatx4 fzero = {0.f, 0.f, 0.f, 0.f};
    floatx4 acc[4];
    #pragma unroll
    for (int tn = 0; tn < 4; ++tn) {
        acc[tn] = fzero;
        #pragma unroll
        for (int ks = 0; ks < 2; ++ks)
            acc[tn] = __builtin_amdgcn_mfma_f32_16x16x32_bf16(
                af[ks], bf[tn][ks], acc[tn], 0, 0, 0);
    }

    float* hp = hl + (size_t)bid * (DSTATE * 64);
    #pragma unroll
    for (int tn = 0; tn < 4; ++tn)
        #pragma unroll
        for (int r = 0; r < 4; ++r)
            hp[(w * 16 + q * 4 + r) * 64 + tn * 16 + a] = acc[tn][r];
    if (tid == 0) Pc[bid] = __expf(La63);
}

// =====================================================================
// SSD phase 2 — element-parallel inter-chunk carry, in place over hl.
// 131072 independent length-32 scans. 512 blocks x 256 threads.
// After this kernel, hl[slot] holds h_start (f32 [n][p]) for chunk slot.
// =====================================================================
__global__ __launch_bounds__(256) void ssd_phase2(
    float* __restrict__ hl, const float* __restrict__ Pc)
{
    const int bid = blockIdx.x;               // bh*16 + eg
    const int bh = bid >> 4;
    const int e = (bid & 15) * 256 + threadIdx.x;   // state element 0..4095

    float carry = 0.f;
    float nxt = hl[(size_t)(bh * NC) * 4096 + e];
    for (int c = 0; c < NC; ++c) {
        const int slot = bh * NC + c;
        const float cur = nxt;
        if (c + 1 < NC) nxt = hl[(size_t)(slot + 1) * 4096 + e];
        const float Pv = Pc[slot];
        hl[(size_t)slot * 4096 + e] = carry;
        carry = fmaf(Pv, carry, cur);
    }
}

// =====================================================================
// SSD phase 3 — 4-wave cooperative block per (b,h,chunk):
//   S^T = B @ C;  W[i][s] = S[i,s] e^(La_i-La_s) (s<=i)
//   Y = diag(e^La) C @ h_start^T + W @ X^T;  yz = Y * silu(z)
//   Wave w owns i-tile w (m1 tn=w, W rows 16w.., m4/m2 row-tile w).
// =====================================================================
__global__ __launch_bounds__(256) void ssd_phase3(
    const float* __restrict__ proj, const u16* __restrict__ xcb,
    const float* __restrict__ hl, const float* __restrict__ LaBuf,
    u16* __restrict__ yz)
{
    __shared__ char lds[34048];
    u32* sBW   = (u32*)lds;              // B natural, then W (aliased)
    u32* sC    = (u32*)(lds + 8448);     // C natural [i][n-pair]
    u32* sXt   = (u32*)(lds + 16896);    // X^T [p][s-pair]
    u32* sH    = (u32*)(lds + 25344);    // h_start^T [p][n-pair]
    float* sLaF = (float*)(lds + 33792); // La[64]
    float* sY  = (float*)(lds + 8448);   // f32 [i][p] 64x66, aliases sC+sXt (epilogue)

    const int bid = blockIdx.x;
    const int c = bid & (NC - 1);
    const int h = (bid >> 5) & (NHEADS - 1);
    const int b = bid >> 9;
    const int tid = threadIdx.x;
    const int w = tid >> 6, ln = tid & 63;
    const int a = ln & 15, q = ln >> 4;
    const int hw = ln >> 5, k32 = ln & 31;
    const size_t r0 = (size_t)b * L_N + c * LC;

    if (tid < 64) sLaF[tid] = LaBuf[(size_t)bid * 64 + tid];

    // stage B, C natural (wave w: rows [16w,16w+16)); X^T, H^T transpose-pack
    const float* hs = hl + (size_t)bid * 4096;
    #pragma unroll
    for (int j = 0; j < 8; ++j) {
        const int rp = w * 8 + j;
        const int row = rp * 2 + hw;
        const float2 vb = *(const float2*)(proj + (r0 + row) * EPROJ + OFF_B + 2 * k32);
        sBW[row * 33 + k32] = pack2(vb.x, vb.y);
        const float2 vc = *(const float2*)(proj + (r0 + row) * EPROJ + OFF_C + 2 * k32);
        sC[row * 33 + k32] = pack2(vc.x, vc.y);

        const int sp_ = rp, s = sp_ * 2;
        const u32 x0 = xcb[(r0 + s) * DINNER + h * 64 + ln];
        const u32 x1 = xcb[(r0 + s + 1) * DINNER + h * 64 + ln];
        sXt[ln * 33 + sp_] = x0 | (x1 << 16);

        sH[ln * 33 + sp_] = pack2(hs[(2 * sp_) * 64 + ln], hs[(2 * sp_ + 1) * 64 + ln]);
    }
    __syncthreads();

    const floatx4 fzero = {0.f, 0.f, 0.f, 0.f};

    // ---- m1: S^T tiles [tm][tn=w], tm<=w ----
    short8 cfr[2], bfr[4][2];
    #pragma unroll
    for (int ks = 0; ks < 2; ++ks)
        cfr[ks] = frag_ld(sC, w * 16 + a, ks * 32 + q * 8);
    #pragma unroll
    for (int tm = 0; tm < 4; ++tm)
        if (tm <= w)
            #pragma unroll
            for (int ks = 0; ks < 2; ++ks)
                bfr[tm][ks] = frag_ld(sBW, tm * 16 + a, ks * 32 + q * 8);
    floatx4 accS[4];
    #pragma unroll
    for (int tm = 0; tm < 4; ++tm) {
        if (tm > w) continue;
        accS[tm] = fzero;
        #pragma unroll
        for (int ks = 0; ks < 2; ++ks)
            accS[tm] = __builtin_amdgcn_mfma_f32_16x16x32_bf16(
                bfr[tm][ks], cfr[ks], accS[tm], 0, 0, 0);
    }
    __syncthreads();   // all waves done reading B before W overwrite

    // ---- build W rows i in [16w,16w+16) ----
    {
        const int i = w * 16 + a;
        const float Li = sLaF[i];
        #pragma unroll
        for (int tm = 0; tm < 4; ++tm) {
            const int d0 = i * 33 + tm * 8 + q * 2;
            if (tm > w) {
                sBW[d0] = 0; sBW[d0 + 1] = 0;
            } else {
                const float4 Ls = *(const float4*)(sLaF + tm * 16 + q * 4);
                float v[4];
                #pragma unroll
                for (int r = 0; r < 4; ++r) {
                    const int s = tm * 16 + q * 4 + r;
                    const float ww = (s <= i) ? __expf(Li - ((const float*)&Ls)[r]) : 0.f;
                    v[r] = accS[tm][r] * ww;
                }
                sBW[d0]     = pack2(v[0], v[1]);
                sBW[d0 + 1] = pack2(v[2], v[3]);
            }
        }
    }

    // ---- m4: accY = C @ h_start^T (row-tile w), scale rows by e^La_i ----
    short8 hfr[4][2];
    #pragma unroll
    for (int tp = 0; tp < 4; ++tp)
        #pragma unroll
        for (int ks = 0; ks < 2; ++ks)
            hfr[tp][ks] = frag_ld(sH, tp * 16 + a, ks * 32 + q * 8);
    floatx4 accY[4];
    #pragma unroll
    for (int tp = 0; tp < 4; ++tp) {
        accY[tp] = fzero;
        #pragma unroll
        for (int ks = 0; ks < 2; ++ks)
            accY[tp] = __builtin_amdgcn_mfma_f32_16x16x32_bf16(
                cfr[ks], hfr[tp][ks], accY[tp], 0, 0, 0);
    }
    {
        const float4 Ls = *(const float4*)(sLaF + w * 16 + q * 4);
        float e4[4];
        #pragma unroll
        for (int r = 0; r < 4; ++r) e4[r] = __expf(((const float*)&Ls)[r]);
        #pragma unroll
        for (int tp = 0; tp < 4; ++tp)
            #pragma unroll
            for (int r = 0; r < 4; ++r) accY[tp][r] *= e4[r];
    }

    // ---- m2: accY += W @ X^T (wave reads only its own W rows) ----
    short8 wfr[2], xfr[4][2];
    #pragma unroll
    for (int ks = 0; ks < 2; ++ks)
        wfr[ks] = frag_ld(sBW, w * 16 + a, ks * 32 + q * 8);
    #pragma unroll
    for (int tp = 0; tp < 4; ++tp)
        #pragma unroll
        for (int ks = 0; ks < 2; ++ks)
            xfr[tp][ks] = frag_ld(sXt, tp * 16 + a, ks * 32 + q * 8);
    #pragma unroll
    for (int tp = 0; tp < 4; ++tp)
        #pragma unroll
        for (int ks = 0; ks < 2; ++ks)
            accY[tp] = __builtin_amdgcn_mfma_f32_16x16x32_bf16(
                wfr[ks], xfr[tp][ks], accY[tp], 0, 0, 0);
    __syncthreads();   // all frag reads of sC/sXt done; safe to alias as sY

    // ---- epilogue: own-rows LDS round-trip, gate, bf16 store ----
    #pragma unroll
    for (int tp = 0; tp < 4; ++tp)
        #pragma unroll
        for (int r = 0; r < 4; ++r)
            sY[(w * 16 + q * 4 + r) * 66 + tp * 16 + a] = accY[tp][r];
    #pragma unroll
    for (int ii = 0; ii < 16; ++ii) {
        const int i = w * 16 + ii;
        const float y = sY[i * 66 + ln];
        const float z = proj[(r0 + i) * EPROJ + OFF_Z + h * 64 + ln];
        yz[(r0 + i) * DINNER + h * 64 + ln] = f2bf(y * silu_f(z));
    }
}

// =====================================================================
extern "C" void kernel_launch(void* const* d_in, const int* in_sizes, int n_in,
                              void* d_out, int out_size, void* d_ws, size_t ws_size,
                              hipStream_t stream)
{
    const float* x       = (const float*)d_in[0];
    const float* W_in    = (const float*)d_in[1];
    const float* conv_w  = (const float*)d_in[2];
    const float* conv_b  = (const float*)d_in[3];
    const float* A_log   = (const float*)d_in[4];
    const float* dt_bias = (const float*)d_in[5];
    const float* W_out   = (const float*)d_in[6];
    float* out = (float*)d_out;

    // workspace layout (~77 MB)
    float* ws    = (float*)d_ws;
    float* proj  = ws;                                          // 4096*2192 f32
    u16*   xcb   = (u16*)(proj + (size_t)4096 * EPROJ);         // 4096*1024 bf16
    float* hl    = (float*)(xcb + (size_t)4096 * DINNER);       // 1024*4096 f32
    float* Pc    = hl + (size_t)1024 * 4096;                    // 1024
    float* LaBuf = Pc + 1024;                                   // 1024*64
    u16*   xbf   = (u16*)(LaBuf + 1024 * 64);                   // 4096*512 bf16
    u16*   wibf  = xbf + (size_t)4096 * DMODEL;                 // 2192*512 bf16
    u16*   wobf  = wibf + (size_t)EPROJ * DMODEL;               // 512*1024 bf16
    u16*   yzbf  = wobf + (size_t)DMODEL * DINNER;              // 4096*1024 bf16

    const int M = B_N * L_N;  // 4096
    const int n0 = M * DMODEL / 4, n1 = EPROJ * DMODEL / 4, n2 = DMODEL * DINNER / 4;

    // 0) fused casts
    cast3_kern<<<(n0 + n1 + n2 + 255) / 256, 256, 0, stream>>>(
        x, xbf, n0, W_in, wibf, n1, W_out, wobf, n2);

    // 1) in_proj: proj = x @ W_in^T  (M=4096, N=2192, K=512)
    gemm_mfma_bt<128, true><<<dim3((EPROJ + 127) / 128, M / 128), 256, 0, stream>>>(
        xbf, wibf, proj, M, EPROJ, DMODEL);

    // 2) conv + silu -> bf16
    conv_silu_kern<<<(M * DINNER) / 256, 256, 0, stream>>>(proj, conv_w, conv_b, xcb);

    // 3) SSD chunked scan (MFMA, 4-wave cooperative)
    ssd_phase1<<<B_N * NHEADS * NC, 256, 0, stream>>>(proj, xcb, A_log, dt_bias, hl, Pc, LaBuf);
    ssd_phase2<<<B_N * NHEADS * 16, 256, 0, stream>>>(hl, Pc);
    ssd_phase3<<<B_N * NHEADS * NC, 256, 0, stream>>>(proj, xcb, hl, LaBuf, yzbf);

    // 4) out_proj: out = yz @ W_out^T  (M=4096, N=512, K=1024)
    gemm_mfma_bt<64, false><<<dim3(DMODEL / 64, M / 128), 256, 0, stream>>>(
        yzbf, wobf, out, M, DMODEL, DINNER);
}

// Round 5
// 161.123 us; speedup vs baseline: 3.2274x; 1.0191x over previous
//
#include <hip/hip_runtime.h>
#include <cstdint>
#include <cstddef>

// ---- problem constants ----
#define B_N     2
#define L_N     2048
#define DMODEL  512
#define DINNER  1024
#define DSTATE  64
#define NHEADS  16
#define EPROJ   2192      // 2*DINNER + 2*DSTATE + NHEADS
#define PB      2176      // bf16 proj row stride (z,x,B,C)
#define OFF_Z   0
#define OFF_XP  1024
#define OFF_B   2048
#define OFF_C   2112
#define LC      64        // scan chunk length (= matmul tile)
#define NC      32        // L_N / LC

typedef unsigned short u16;
typedef unsigned int   u32;
typedef __attribute__((ext_vector_type(8))) short short8;   // 8 bf16 (4 VGPRs)
typedef __attribute__((ext_vector_type(4))) float floatx4;  // MFMA acc

__device__ __forceinline__ float silu_f(float v) { return v / (1.f + __expf(-v)); }

__device__ __forceinline__ u16 f2bf(float f) {
    union { float f; uint32_t u; } v; v.f = f;
    uint32_t r = (v.u + 0x7FFFu + ((v.u >> 16) & 1u)) >> 16;  // RNE
    return (u16)r;
}

__device__ __forceinline__ float bf2f(u16 b) {
    union { u32 u; float f; } v; v.u = (u32)b << 16; return v.f;
}

__device__ __forceinline__ u32 pack2(float lo, float hi) {
    return (u32)f2bf(lo) | ((u32)f2bf(hi) << 16);
}

__device__ __forceinline__ float lane_bcast(float v, int n) {
    union { float f; uint32_t u; } a, b;
    a.f = v;
    b.u = __builtin_amdgcn_readlane(a.u, n);
    return b.f;
}

// read bf16 fragment A[row][k0..k0+7] from pair-packed LDS tile (stride 33 dwords)
__device__ __forceinline__ short8 frag_ld(const u32* s, int row, int k0) {
    const u32* q = s + row * 33 + (k0 >> 1);
    union { u32 u[4]; short8 v; } r;
    r.u[0] = q[0]; r.u[1] = q[1]; r.u[2] = q[2]; r.u[3] = q[3];
    return r.v;
}

__device__ __forceinline__ void gload_lds16(const u16* g, u16* s) {
    __builtin_amdgcn_global_load_lds(
        (const __attribute__((address_space(1))) void*)g,
        (__attribute__((address_space(3))) void*)s,
        16, 0, 0);
}

// =====================================================================
// fused fp32 -> bf16 cast for x, W_in, W_out (one launch). n's in float4 quads.
// =====================================================================
__global__ __launch_bounds__(256) void cast3_kern(
    const float* __restrict__ s0, u16* __restrict__ d0, int n0,
    const float* __restrict__ s1, u16* __restrict__ d1, int n1,
    const float* __restrict__ s2, u16* __restrict__ d2, int n2)
{
    int i = blockIdx.x * 256 + threadIdx.x;
    const float* s; u16* d;
    if (i < n0)           { s = s0; d = d0; }
    else if (i < n0 + n1) { i -= n0; s = s1; d = d1; }
    else                  { i -= n0 + n1; if (i >= n2) return; s = s2; d = d2; }
    float4 v = ((const float4*)s)[i];
    ushort4 o;
    o.x = f2bf(v.x); o.y = f2bf(v.y); o.z = f2bf(v.z); o.w = f2bf(v.w);
    ((ushort4*)d)[i] = o;
}

// =====================================================================
// bf16 MFMA GEMM, generalized (m97 pattern).
//   C = A[M,K] @ Bt[N,K]^T.  4 waves as 2x2; wave tile (BM/2)x(BN/2).
// PSPLIT epilogue: col<2176 -> bf16 projb (stride 2176);
//                  2176<=col<2192 -> f32 dtf (stride 16). Else f32 Cf[M,N].
// =====================================================================
template<int BM, int BN, bool GUARD, bool PSPLIT>
__global__ __launch_bounds__(256) void gemm_mfma_bt(
    const u16* __restrict__ A, const u16* __restrict__ Bt,
    float* __restrict__ Cf, u16* __restrict__ Cb, float* __restrict__ Dt,
    int M, int N, int K)
{
    constexpr int MI = BM / 32;
    constexpr int NI = BN / 32;
    __shared__ u16 As[BM * 32];
    __shared__ u16 Bs[BN * 32];

    const int tid = threadIdx.x;
    const int w   = tid >> 6;
    const int ln  = tid & 63;
    const int wm  = w >> 1, wn = w & 1;
    const int bm  = blockIdx.y * BM;
    const int bn  = blockIdx.x * BN;

    const int srow = ln >> 2;
    const int skq  = (ln & 3) * 8;
    const int fr = ln & 15;
    const int fq = (ln >> 4) * 8;

    floatx4 acc[MI][NI];
    const floatx4 fzero = {0.f, 0.f, 0.f, 0.f};
    #pragma unroll
    for (int mi = 0; mi < MI; ++mi)
        #pragma unroll
        for (int ni = 0; ni < NI; ++ni) acc[mi][ni] = fzero;

    for (int k0 = 0; k0 < K; k0 += 32) {
        #pragma unroll
        for (int r = 0; r < BM / 64; ++r) {
            const int row = r * 64 + w * 16 + srow;
            gload_lds16(A + (size_t)(bm + row) * K + k0 + skq,
                        &As[(r * 64 + w * 16) * 32]);
        }
        #pragma unroll
        for (int r = 0; r < BN / 64; ++r) {
            const int row = r * 64 + w * 16 + srow;
            int rn = bn + row;
            if (GUARD) rn = (rn < N) ? rn : (N - 1);
            gload_lds16(Bt + (size_t)rn * K + k0 + skq,
                        &Bs[(r * 64 + w * 16) * 32]);
        }
        __syncthreads();

        short8 af[MI], bf[NI];
        #pragma unroll
        for (int mi = 0; mi < MI; ++mi)
            af[mi] = *(const short8*)&As[(wm * (BM / 2) + mi * 16 + fr) * 32 + fq];
        #pragma unroll
        for (int ni = 0; ni < NI; ++ni)
            bf[ni] = *(const short8*)&Bs[(wn * (BN / 2) + ni * 16 + fr) * 32 + fq];
        #pragma unroll
        for (int mi = 0; mi < MI; ++mi)
            #pragma unroll
            for (int ni = 0; ni < NI; ++ni)
                acc[mi][ni] = __builtin_amdgcn_mfma_f32_16x16x32_bf16(
                    af[mi], bf[ni], acc[mi][ni], 0, 0, 0);
        __syncthreads();
    }

    const int cr = (ln >> 4) * 4;
    const int cc = ln & 15;
    #pragma unroll
    for (int mi = 0; mi < MI; ++mi) {
        const int row0 = bm + wm * (BM / 2) + mi * 16 + cr;
        #pragma unroll
        for (int ni = 0; ni < NI; ++ni) {
            const int col = bn + wn * (BN / 2) + ni * 16 + cc;
            #pragma unroll
            for (int r = 0; r < 4; ++r) {
                const int row = row0 + r;
                const float v = acc[mi][ni][r];
                if (PSPLIT) {
                    if (col < PB)
                        Cb[(size_t)row * PB + col] = f2bf(v);
                    else if (col < EPROJ)
                        Dt[(size_t)row * 16 + (col - PB)] = v;
                } else {
                    Cf[(size_t)row * N + col] = v;
                }
            }
        }
    }
}

// =====================================================================
// Depthwise causal conv (k=4, left pad 3) + bias + SiLU; bf16 in/out.
// =====================================================================
__global__ __launch_bounds__(256) void conv_silu_kern(
    const u16* __restrict__ projb, const float* __restrict__ cw,
    const float* __restrict__ cb, u16* __restrict__ xcb)
{
    const int idx = blockIdx.x * 256 + threadIdx.x;   // over B*L*DINNER
    const int c = idx & (DINNER - 1);
    const int t = (idx >> 10) & (L_N - 1);
    const int b = idx >> 21;

    float acc = cb[c];
    #pragma unroll
    for (int k = 0; k < 4; ++k) {
        const int tt = t - 3 + k;
        if (tt >= 0)
            acc += bf2f(projb[((size_t)(b * L_N + tt)) * PB + OFF_XP + c]) * cw[c * 4 + k];
    }
    xcb[idx] = f2bf(silu_f(acc));
}

// =====================================================================
// SSD phase 1 — 4-wave cooperative block per (b,h,chunk):
//   dt from f32 dtf; La = cumsum(logdA);
//   Hc[n][p] = sum_s e^(La63-La_s) B[s][n] X[s][p]  (MFMA, wave w = tile-row w)
// =====================================================================
__global__ __launch_bounds__(256) void ssd_phase1(
    const u16* __restrict__ projb, const float* __restrict__ dtf,
    const u16* __restrict__ xcb,
    const float* __restrict__ A_log, const float* __restrict__ dt_bias,
    float* __restrict__ hl, float* __restrict__ Pc, float* __restrict__ LaBuf)
{
    __shared__ u32 sBD[64 * 33];   // (e^(La63-La_s) B[s][n])^T : [n][s-pair]
    __shared__ u32 sXt[64 * 33];   // X^T: [p][s-pair]

    const int bid = blockIdx.x;               // ((b*16+h)*32 + c)
    const int c = bid & (NC - 1);
    const int h = (bid >> 5) & (NHEADS - 1);
    const int b = bid >> 9;
    const int tid = threadIdx.x;
    const int w = tid >> 6, ln = tid & 63;
    const int a = ln & 15, q = ln >> 4;
    const size_t r0 = (size_t)b * L_N + c * LC;

    // logdA + inclusive cumsum (redundant per wave; all waves identical)
    float dt = dtf[(r0 + ln) * 16 + h] + dt_bias[h];
    float sp = (dt > 15.f) ? dt : log1pf(__expf(dt));
    float La = sp * (-__expf(A_log[h]));
    #pragma unroll
    for (int d = 1; d < 64; d <<= 1) {
        float up = __shfl_up(La, d, 64);
        if (ln >= d) La += up;
    }
    if (w == 0) LaBuf[(size_t)bid * 64 + ln] = La;
    const float La63 = lane_bcast(La, 63);

    // staging: wave w covers s-pairs [w*8, w*8+8)
    #pragma unroll
    for (int j = 0; j < 8; ++j) {
        const int sp_ = w * 8 + j, s = sp_ * 2;
        const float w0 = __expf(La63 - lane_bcast(La, s));
        const float w1 = __expf(La63 - lane_bcast(La, s + 1));
        const float b0 = bf2f(projb[(r0 + s) * PB + OFF_B + ln]) * w0;
        const float b1 = bf2f(projb[(r0 + s + 1) * PB + OFF_B + ln]) * w1;
        sBD[ln * 33 + sp_] = pack2(b0, b1);
        const u32 x0 = xcb[(r0 + s) * DINNER + h * 64 + ln];
        const u32 x1 = xcb[(r0 + s + 1) * DINNER + h * 64 + ln];
        sXt[ln * 33 + sp_] = x0 | (x1 << 16);
    }
    __syncthreads();

    // MFMA: wave w computes output tile-row tm=w (rows n in [16w,16w+16))
    short8 af[2], bf[4][2];
    #pragma unroll
    for (int ks = 0; ks < 2; ++ks)
        af[ks] = frag_ld(sBD, w * 16 + a, ks * 32 + q * 8);
    #pragma unroll
    for (int tn = 0; tn < 4; ++tn)
        #pragma unroll
        for (int ks = 0; ks < 2; ++ks)
            bf[tn][ks] = frag_ld(sXt, tn * 16 + a, ks * 32 + q * 8);

    const floatx4 fzero = {0.f, 0.f, 0.f, 0.f};
    floatx4 acc[4];
    #pragma unroll
    for (int tn = 0; tn < 4; ++tn) {
        acc[tn] = fzero;
        #pragma unroll
        for (int ks = 0; ks < 2; ++ks)
            acc[tn] = __builtin_amdgcn_mfma_f32_16x16x32_bf16(
                af[ks], bf[tn][ks], acc[tn], 0, 0, 0);
    }

    float* hp = hl + (size_t)bid * (DSTATE * 64);
    #pragma unroll
    for (int tn = 0; tn < 4; ++tn)
        #pragma unroll
        for (int r = 0; r < 4; ++r)
            hp[(w * 16 + q * 4 + r) * 64 + tn * 16 + a] = acc[tn][r];
    if (tid == 0) Pc[bid] = __expf(La63);
}

// =====================================================================
// SSD phase 2 — element-parallel inter-chunk carry, in place over hl.
// =====================================================================
__global__ __launch_bounds__(256) void ssd_phase2(
    float* __restrict__ hl, const float* __restrict__ Pc)
{
    const int bid = blockIdx.x;               // bh*16 + eg
    const int bh = bid >> 4;
    const int e = (bid & 15) * 256 + threadIdx.x;   // state element 0..4095

    float carry = 0.f;
    float nxt = hl[(size_t)(bh * NC) * 4096 + e];
    for (int c = 0; c < NC; ++c) {
        const int slot = bh * NC + c;
        const float cur = nxt;
        if (c + 1 < NC) nxt = hl[(size_t)(slot + 1) * 4096 + e];
        const float Pv = Pc[slot];
        hl[(size_t)slot * 4096 + e] = carry;
        carry = fmaf(Pv, carry, cur);
    }
}

// =====================================================================
// SSD phase 3 — 4-wave cooperative block per (b,h,chunk):
//   S^T = B @ C;  W[i][s] = S[i,s] e^(La_i-La_s) (s<=i)
//   Y = diag(e^La) C @ h_start^T + W @ X^T;  yz = Y * silu(z)
// =====================================================================
__global__ __launch_bounds__(256) void ssd_phase3(
    const u16* __restrict__ projb, const u16* __restrict__ xcb,
    const float* __restrict__ hl, const float* __restrict__ LaBuf,
    u16* __restrict__ yz)
{
    __shared__ char lds[34048];
    u32* sBW   = (u32*)lds;              // B natural, then W (aliased)
    u32* sC    = (u32*)(lds + 8448);     // C natural [i][n-pair]
    u32* sXt   = (u32*)(lds + 16896);    // X^T [p][s-pair]
    u32* sH    = (u32*)(lds + 25344);    // h_start^T [p][n-pair]
    float* sLaF = (float*)(lds + 33792); // La[64]
    float* sY  = (float*)(lds + 8448);   // f32 [i][p] 64x66, aliases sC+sXt (epilogue)

    const int bid = blockIdx.x;
    const int c = bid & (NC - 1);
    const int h = (bid >> 5) & (NHEADS - 1);
    const int b = bid >> 9;
    const int tid = threadIdx.x;
    const int w = tid >> 6, ln = tid & 63;
    const int a = ln & 15, q = ln >> 4;
    const int hw = ln >> 5, k32 = ln & 31;
    const size_t r0 = (size_t)b * L_N + c * LC;

    if (tid < 64) sLaF[tid] = LaBuf[(size_t)bid * 64 + tid];

    // stage B, C natural (raw bf16-pair copies); X^T, H^T transpose-pack
    const float* hs = hl + (size_t)bid * 4096;
    #pragma unroll
    for (int j = 0; j < 8; ++j) {
        const int rp = w * 8 + j;
        const int row = rp * 2 + hw;
        sBW[row * 33 + k32] = *(const u32*)(projb + (r0 + row) * PB + OFF_B + 2 * k32);
        sC [row * 33 + k32] = *(const u32*)(projb + (r0 + row) * PB + OFF_C + 2 * k32);

        const int sp_ = rp, s = sp_ * 2;
        const u32 x0 = xcb[(r0 + s) * DINNER + h * 64 + ln];
        const u32 x1 = xcb[(r0 + s + 1) * DINNER + h * 64 + ln];
        sXt[ln * 33 + sp_] = x0 | (x1 << 16);

        sH[ln * 33 + sp_] = pack2(hs[(2 * sp_) * 64 + ln], hs[(2 * sp_ + 1) * 64 + ln]);
    }
    __syncthreads();

    const floatx4 fzero = {0.f, 0.f, 0.f, 0.f};

    // ---- m1: S^T tiles [tm][tn=w], tm<=w ----
    short8 cfr[2], bfr[4][2];
    #pragma unroll
    for (int ks = 0; ks < 2; ++ks)
        cfr[ks] = frag_ld(sC, w * 16 + a, ks * 32 + q * 8);
    #pragma unroll
    for (int tm = 0; tm < 4; ++tm)
        if (tm <= w)
            #pragma unroll
            for (int ks = 0; ks < 2; ++ks)
                bfr[tm][ks] = frag_ld(sBW, tm * 16 + a, ks * 32 + q * 8);
    floatx4 accS[4];
    #pragma unroll
    for (int tm = 0; tm < 4; ++tm) {
        if (tm > w) continue;
        accS[tm] = fzero;
        #pragma unroll
        for (int ks = 0; ks < 2; ++ks)
            accS[tm] = __builtin_amdgcn_mfma_f32_16x16x32_bf16(
                bfr[tm][ks], cfr[ks], accS[tm], 0, 0, 0);
    }
    __syncthreads();   // all waves done reading B before W overwrite

    // ---- build W rows i in [16w,16w+16) ----
    {
        const int i = w * 16 + a;
        const float Li = sLaF[i];
        #pragma unroll
        for (int tm = 0; tm < 4; ++tm) {
            const int d0 = i * 33 + tm * 8 + q * 2;
            if (tm > w) {
                sBW[d0] = 0; sBW[d0 + 1] = 0;
            } else {
                const float4 Ls = *(const float4*)(sLaF + tm * 16 + q * 4);
                float v[4];
                #pragma unroll
                for (int r = 0; r < 4; ++r) {
                    const int s = tm * 16 + q * 4 + r;
                    const float ww = (s <= i) ? __expf(Li - ((const float*)&Ls)[r]) : 0.f;
                    v[r] = accS[tm][r] * ww;
                }
                sBW[d0]     = pack2(v[0], v[1]);
                sBW[d0 + 1] = pack2(v[2], v[3]);
            }
        }
    }

    // ---- m4: accY = C @ h_start^T (row-tile w), scale rows by e^La_i ----
    short8 hfr[4][2];
    #pragma unroll
    for (int tp = 0; tp < 4; ++tp)
        #pragma unroll
        for (int ks = 0; ks < 2; ++ks)
            hfr[tp][ks] = frag_ld(sH, tp * 16 + a, ks * 32 + q * 8);
    floatx4 accY[4];
    #pragma unroll
    for (int tp = 0; tp < 4; ++tp) {
        accY[tp] = fzero;
        #pragma unroll
        for (int ks = 0; ks < 2; ++ks)
            accY[tp] = __builtin_amdgcn_mfma_f32_16x16x32_bf16(
                cfr[ks], hfr[tp][ks], accY[tp], 0, 0, 0);
    }
    {
        const float4 Ls = *(const float4*)(sLaF + w * 16 + q * 4);
        float e4[4];
        #pragma unroll
        for (int r = 0; r < 4; ++r) e4[r] = __expf(((const float*)&Ls)[r]);
        #pragma unroll
        for (int tp = 0; tp < 4; ++tp)
            #pragma unroll
            for (int r = 0; r < 4; ++r) accY[tp][r] *= e4[r];
    }

    // ---- m2: accY += W @ X^T (wave reads only its own W rows) ----
    short8 wfr[2], xfr[4][2];
    #pragma unroll
    for (int ks = 0; ks < 2; ++ks)
        wfr[ks] = frag_ld(sBW, w * 16 + a, ks * 32 + q * 8);
    #pragma unroll
    for (int tp = 0; tp < 4; ++tp)
        #pragma unroll
        for (int ks = 0; ks < 2; ++ks)
            xfr[tp][ks] = frag_ld(sXt, tp * 16 + a, ks * 32 + q * 8);
    #pragma unroll
    for (int tp = 0; tp < 4; ++tp)
        #pragma unroll
        for (int ks = 0; ks < 2; ++ks)
            accY[tp] = __builtin_amdgcn_mfma_f32_16x16x32_bf16(
                wfr[ks], xfr[tp][ks], accY[tp], 0, 0, 0);
    __syncthreads();   // all frag reads of sC/sXt done; safe to alias as sY

    // ---- epilogue: own-rows LDS round-trip, gate (bf16 z), bf16 store ----
    #pragma unroll
    for (int tp = 0; tp < 4; ++tp)
        #pragma unroll
        for (int r = 0; r < 4; ++r)
            sY[(w * 16 + q * 4 + r) * 66 + tp * 16 + a] = accY[tp][r];
    #pragma unroll
    for (int ii = 0; ii < 16; ++ii) {
        const int i = w * 16 + ii;
        const float y = sY[i * 66 + ln];
        const float z = bf2f(projb[(r0 + i) * PB + OFF_Z + h * 64 + ln]);
        yz[(r0 + i) * DINNER + h * 64 + ln] = f2bf(y * silu_f(z));
    }
}

// =====================================================================
extern "C" void kernel_launch(void* const* d_in, const int* in_sizes, int n_in,
                              void* d_out, int out_size, void* d_ws, size_t ws_size,
                              hipStream_t stream)
{
    const float* x       = (const float*)d_in[0];
    const float* W_in    = (const float*)d_in[1];
    const float* conv_w  = (const float*)d_in[2];
    const float* conv_b  = (const float*)d_in[3];
    const float* A_log   = (const float*)d_in[4];
    const float* dt_bias = (const float*)d_in[5];
    const float* W_out   = (const float*)d_in[6];
    float* out = (float*)d_out;

    // workspace layout (~59 MB)
    u16*   projb = (u16*)d_ws;                                  // 4096*2176 bf16
    float* dtf   = (float*)(projb + (size_t)4096 * PB);         // 4096*16 f32
    u16*   xcb   = (u16*)(dtf + (size_t)4096 * 16);             // 4096*1024 bf16
    float* hl    = (float*)(xcb + (size_t)4096 * DINNER);       // 1024*4096 f32
    float* Pc    = hl + (size_t)1024 * 4096;                    // 1024
    float* LaBuf = Pc + 1024;                                   // 1024*64
    u16*   xbf   = (u16*)(LaBuf + 1024 * 64);                   // 4096*512 bf16
    u16*   wibf  = xbf + (size_t)4096 * DMODEL;                 // 2192*512 bf16
    u16*   wobf  = wibf + (size_t)EPROJ * DMODEL;               // 512*1024 bf16
    u16*   yzbf  = wobf + (size_t)DMODEL * DINNER;              // 4096*1024 bf16

    const int M = B_N * L_N;  // 4096
    const int n0 = M * DMODEL / 4, n1 = EPROJ * DMODEL / 4, n2 = DMODEL * DINNER / 4;

    // 0) fused casts
    cast3_kern<<<(n0 + n1 + n2 + 255) / 256, 256, 0, stream>>>(
        x, xbf, n0, W_in, wibf, n1, W_out, wobf, n2);

    // 1) in_proj: proj = x @ W_in^T  (M=4096, N=2192, K=512) -> bf16 projb + f32 dtf
    gemm_mfma_bt<128, 128, true, true><<<dim3((EPROJ + 127) / 128, M / 128), 256, 0, stream>>>(
        xbf, wibf, nullptr, projb, dtf, M, EPROJ, DMODEL);

    // 2) conv + silu -> bf16
    conv_silu_kern<<<(M * DINNER) / 256, 256, 0, stream>>>(projb, conv_w, conv_b, xcb);

    // 3) SSD chunked scan (MFMA, 4-wave cooperative)
    ssd_phase1<<<B_N * NHEADS * NC, 256, 0, stream>>>(projb, dtf, xcb, A_log, dt_bias, hl, Pc, LaBuf);
    ssd_phase2<<<B_N * NHEADS * 16, 256, 0, stream>>>(hl, Pc);
    ssd_phase3<<<B_N * NHEADS * NC, 256, 0, stream>>>(projb, xcb, hl, LaBuf, yzbf);

    // 4) out_proj: out = yz @ W_out^T  (M=4096, N=512, K=1024), 512 blocks (2/CU)
    gemm_mfma_bt<64, 64, false, false><<<dim3(DMODEL / 64, M / 64), 256, 0, stream>>>(
        yzbf, wobf, out, nullptr, nullptr, M, DMODEL, DINNER);
}

// Round 6
// 154.410 us; speedup vs baseline: 3.3677x; 1.0435x over previous
//
#include <hip/hip_runtime.h>
#include <cstdint>
#include <cstddef>

// ---- problem constants ----
#define B_N     2
#define L_N     2048
#define DMODEL  512
#define DINNER  1024
#define DSTATE  64
#define NHEADS  16
#define EPROJ   2192      // 2*DINNER + 2*DSTATE + NHEADS
#define PB      2176      // bf16 proj row stride (z,x,B,C)
#define OFF_Z   0
#define OFF_XP  1024
#define OFF_B   2048
#define OFF_C   2112
#define LC      64        // scan chunk length (= matmul tile)
#define NC      32        // L_N / LC

typedef unsigned short u16;
typedef unsigned int   u32;
typedef __attribute__((ext_vector_type(8))) short short8;   // 8 bf16 (4 VGPRs)
typedef __attribute__((ext_vector_type(4))) float floatx4;  // MFMA acc

__device__ __forceinline__ float silu_f(float v) { return v / (1.f + __expf(-v)); }

__device__ __forceinline__ u16 f2bf(float f) {
    union { float f; uint32_t u; } v; v.f = f;
    uint32_t r = (v.u + 0x7FFFu + ((v.u >> 16) & 1u)) >> 16;  // RNE
    return (u16)r;
}

__device__ __forceinline__ float bf2f(u16 b) {
    union { u32 u; float f; } v; v.u = (u32)b << 16; return v.f;
}

__device__ __forceinline__ u32 pack2(float lo, float hi) {
    return (u32)f2bf(lo) | ((u32)f2bf(hi) << 16);
}

__device__ __forceinline__ float lane_bcast(float v, int n) {
    union { float f; uint32_t u; } a, b;
    a.f = v;
    b.u = __builtin_amdgcn_readlane(a.u, n);
    return b.f;
}

// read bf16 fragment A[row][k0..k0+7] from pair-packed LDS tile (stride 33 dwords)
__device__ __forceinline__ short8 frag_ld(const u32* s, int row, int k0) {
    const u32* q = s + row * 33 + (k0 >> 1);
    union { u32 u[4]; short8 v; } r;
    r.u[0] = q[0]; r.u[1] = q[1]; r.u[2] = q[2]; r.u[3] = q[3];
    return r.v;
}

__device__ __forceinline__ void gload_lds16(const u16* g, u16* s) {
    __builtin_amdgcn_global_load_lds(
        (const __attribute__((address_space(1))) void*)g,
        (__attribute__((address_space(3))) void*)s,
        16, 0, 0);
}

// =====================================================================
// fused fp32 -> bf16 cast for x, W_in, W_out (one launch). n's in float4 quads.
// =====================================================================
__global__ __launch_bounds__(256) void cast3_kern(
    const float* __restrict__ s0, u16* __restrict__ d0, int n0,
    const float* __restrict__ s1, u16* __restrict__ d1, int n1,
    const float* __restrict__ s2, u16* __restrict__ d2, int n2)
{
    int i = blockIdx.x * 256 + threadIdx.x;
    const float* s; u16* d;
    if (i < n0)           { s = s0; d = d0; }
    else if (i < n0 + n1) { i -= n0; s = s1; d = d1; }
    else                  { i -= n0 + n1; if (i >= n2) return; s = s2; d = d2; }
    float4 v = ((const float4*)s)[i];
    ushort4 o;
    o.x = f2bf(v.x); o.y = f2bf(v.y); o.z = f2bf(v.z); o.w = f2bf(v.w);
    ((ushort4*)d)[i] = o;
}

// =====================================================================
// bf16 MFMA GEMM, generalized (m97 pattern).
//   C = A[M,K] @ Bt[N,K]^T.  4 waves as 2x2; wave tile (BM/2)x(BN/2).
// PSPLIT epilogue: col<2176 -> bf16 projb (stride 2176);
//                  2176<=col<2192 -> f32 dtf (stride 16). Else f32 Cf[M,N].
// =====================================================================
template<int BM, int BN, bool GUARD, bool PSPLIT>
__global__ __launch_bounds__(256) void gemm_mfma_bt(
    const u16* __restrict__ A, const u16* __restrict__ Bt,
    float* __restrict__ Cf, u16* __restrict__ Cb, float* __restrict__ Dt,
    int M, int N, int K)
{
    constexpr int MI = BM / 32;
    constexpr int NI = BN / 32;
    __shared__ u16 As[BM * 32];
    __shared__ u16 Bs[BN * 32];

    const int tid = threadIdx.x;
    const int w   = tid >> 6;
    const int ln  = tid & 63;
    const int wm  = w >> 1, wn = w & 1;
    const int bm  = blockIdx.y * BM;
    const int bn  = blockIdx.x * BN;

    const int srow = ln >> 2;
    const int skq  = (ln & 3) * 8;
    const int fr = ln & 15;
    const int fq = (ln >> 4) * 8;

    floatx4 acc[MI][NI];
    const floatx4 fzero = {0.f, 0.f, 0.f, 0.f};
    #pragma unroll
    for (int mi = 0; mi < MI; ++mi)
        #pragma unroll
        for (int ni = 0; ni < NI; ++ni) acc[mi][ni] = fzero;

    for (int k0 = 0; k0 < K; k0 += 32) {
        #pragma unroll
        for (int r = 0; r < BM / 64; ++r) {
            const int row = r * 64 + w * 16 + srow;
            gload_lds16(A + (size_t)(bm + row) * K + k0 + skq,
                        &As[(r * 64 + w * 16) * 32]);
        }
        #pragma unroll
        for (int r = 0; r < BN / 64; ++r) {
            const int row = r * 64 + w * 16 + srow;
            int rn = bn + row;
            if (GUARD) rn = (rn < N) ? rn : (N - 1);
            gload_lds16(Bt + (size_t)rn * K + k0 + skq,
                        &Bs[(r * 64 + w * 16) * 32]);
        }
        __syncthreads();

        short8 af[MI], bf[NI];
        #pragma unroll
        for (int mi = 0; mi < MI; ++mi)
            af[mi] = *(const short8*)&As[(wm * (BM / 2) + mi * 16 + fr) * 32 + fq];
        #pragma unroll
        for (int ni = 0; ni < NI; ++ni)
            bf[ni] = *(const short8*)&Bs[(wn * (BN / 2) + ni * 16 + fr) * 32 + fq];
        #pragma unroll
        for (int mi = 0; mi < MI; ++mi)
            #pragma unroll
            for (int ni = 0; ni < NI; ++ni)
                acc[mi][ni] = __builtin_amdgcn_mfma_f32_16x16x32_bf16(
                    af[mi], bf[ni], acc[mi][ni], 0, 0, 0);
        __syncthreads();
    }

    const int cr = (ln >> 4) * 4;
    const int cc = ln & 15;
    #pragma unroll
    for (int mi = 0; mi < MI; ++mi) {
        const int row0 = bm + wm * (BM / 2) + mi * 16 + cr;
        #pragma unroll
        for (int ni = 0; ni < NI; ++ni) {
            const int col = bn + wn * (BN / 2) + ni * 16 + cc;
            #pragma unroll
            for (int r = 0; r < 4; ++r) {
                const int row = row0 + r;
                const float v = acc[mi][ni][r];
                if (PSPLIT) {
                    if (col < PB)
                        Cb[(size_t)row * PB + col] = f2bf(v);
                    else if (col < EPROJ)
                        Dt[(size_t)row * 16 + (col - PB)] = v;
                } else {
                    Cf[(size_t)row * N + col] = v;
                }
            }
        }
    }
}

// =====================================================================
// SSD phase 1 — 4-wave cooperative block per (b,h,chunk), conv fused:
//   stage raw x slice (67x64 bf16) -> conv+silu during X^T pack;
//   La = cumsum(logdA);  Hc = (e^(La63-La_s) B)^T @ X  (MFMA)
// =====================================================================
__global__ __launch_bounds__(256) void ssd_phase1(
    const u16* __restrict__ projb, const float* __restrict__ dtf,
    const float* __restrict__ cw, const float* __restrict__ cb,
    const float* __restrict__ A_log, const float* __restrict__ dt_bias,
    float* __restrict__ hl, float* __restrict__ Pc, float* __restrict__ LaBuf)
{
    __shared__ u32 sBD[64 * 33];   // (e^(La63-La_s) B[s][n])^T : [n][s-pair]
    __shared__ u32 sXt[64 * 33];   // X^T: [p][s-pair]
    __shared__ u32 sXr[67 * 32];   // raw x rows r0-3..r0+63 (bf16 pairs)
    const u16* sXr16 = (const u16*)sXr;

    const int bid = blockIdx.x;               // ((b*16+h)*32 + c)
    const int c = bid & (NC - 1);
    const int h = (bid >> 5) & (NHEADS - 1);
    const int b = bid >> 9;
    const int tid = threadIdx.x;
    const int w = tid >> 6, ln = tid & 63;
    const int a = ln & 15, q = ln >> 4;
    const size_t r0 = (size_t)b * L_N + c * LC;
    const int tl0 = c * LC - 3;               // local time of LDS row 0

    // logdA + inclusive cumsum (redundant per wave; all waves identical)
    float dt = dtf[(r0 + ln) * 16 + h] + dt_bias[h];
    float sp = (dt > 15.f) ? dt : log1pf(__expf(dt));
    float La = sp * (-__expf(A_log[h]));
    #pragma unroll
    for (int d = 1; d < 64; d <<= 1) {
        float up = __shfl_up(La, d, 64);
        if (ln >= d) La += up;
    }
    if (w == 0) LaBuf[(size_t)bid * 64 + ln] = La;
    const float La63 = lane_bcast(La, 63);

    // stage raw x slice (zero-fill t<0)
    for (int idx = tid; idx < 67 * 32; idx += 256) {
        const int row = idx >> 5, c2 = idx & 31;
        u32 v = 0;
        if (tl0 + row >= 0)
            v = *(const u32*)(projb + ((size_t)b * L_N + tl0 + row) * PB + OFF_XP + h * 64 + 2 * c2);
        sXr[idx] = v;
    }
    __syncthreads();

    const int ch = h * 64 + ln;
    const float4 w4 = *(const float4*)(cw + ch * 4);
    const float bias = cb[ch];

    // staging: wave w covers s-pairs [w*8, w*8+8); conv+silu inline
    #pragma unroll
    for (int j = 0; j < 8; ++j) {
        const int sp_ = w * 8 + j, s = sp_ * 2;
        float a0 = bias, a1 = bias;
        #pragma unroll
        for (int k = 0; k < 4; ++k) {
            a0 += bf2f(sXr16[(s + k) * 64 + ln]) * ((const float*)&w4)[k];
            a1 += bf2f(sXr16[(s + 1 + k) * 64 + ln]) * ((const float*)&w4)[k];
        }
        const float x0 = silu_f(a0), x1 = silu_f(a1);
        const float w0 = __expf(La63 - lane_bcast(La, s));
        const float w1 = __expf(La63 - lane_bcast(La, s + 1));
        const float b0 = bf2f(projb[(r0 + s) * PB + OFF_B + ln]) * w0;
        const float b1 = bf2f(projb[(r0 + s + 1) * PB + OFF_B + ln]) * w1;
        sBD[ln * 33 + sp_] = pack2(b0, b1);
        sXt[ln * 33 + sp_] = pack2(x0, x1);
    }
    __syncthreads();

    // MFMA: wave w computes output tile-row tm=w (rows n in [16w,16w+16))
    short8 af[2], bf[4][2];
    #pragma unroll
    for (int ks = 0; ks < 2; ++ks)
        af[ks] = frag_ld(sBD, w * 16 + a, ks * 32 + q * 8);
    #pragma unroll
    for (int tn = 0; tn < 4; ++tn)
        #pragma unroll
        for (int ks = 0; ks < 2; ++ks)
            bf[tn][ks] = frag_ld(sXt, tn * 16 + a, ks * 32 + q * 8);

    const floatx4 fzero = {0.f, 0.f, 0.f, 0.f};
    floatx4 acc[4];
    #pragma unroll
    for (int tn = 0; tn < 4; ++tn) {
        acc[tn] = fzero;
        #pragma unroll
        for (int ks = 0; ks < 2; ++ks)
            acc[tn] = __builtin_amdgcn_mfma_f32_16x16x32_bf16(
                af[ks], bf[tn][ks], acc[tn], 0, 0, 0);
    }

    float* hp = hl + (size_t)bid * (DSTATE * 64);
    #pragma unroll
    for (int tn = 0; tn < 4; ++tn)
        #pragma unroll
        for (int r = 0; r < 4; ++r)
            hp[(w * 16 + q * 4 + r) * 64 + tn * 16 + a] = acc[tn][r];
    if (tid == 0) Pc[bid] = __expf(La63);
}

// =====================================================================
// SSD phase 2 — element-parallel inter-chunk carry, in place over hl.
// =====================================================================
__global__ __launch_bounds__(256) void ssd_phase2(
    float* __restrict__ hl, const float* __restrict__ Pc)
{
    const int bid = blockIdx.x;               // bh*16 + eg
    const int bh = bid >> 4;
    const int e = (bid & 15) * 256 + threadIdx.x;   // state element 0..4095

    float carry = 0.f;
    float nxt = hl[(size_t)(bh * NC) * 4096 + e];
    for (int c = 0; c < NC; ++c) {
        const int slot = bh * NC + c;
        const float cur = nxt;
        if (c + 1 < NC) nxt = hl[(size_t)(slot + 1) * 4096 + e];
        const float Pv = Pc[slot];
        hl[(size_t)slot * 4096 + e] = carry;
        carry = fmaf(Pv, carry, cur);
    }
}

// =====================================================================
// SSD phase 3 — 4-wave cooperative block per (b,h,chunk), conv fused:
//   S^T = B @ C;  W[i][s] = S[i,s] e^(La_i-La_s) (s<=i)
//   Y = diag(e^La) C @ h_start^T + W @ X^T;  yz = Y * silu(z)
// =====================================================================
__global__ __launch_bounds__(256) void ssd_phase3(
    const u16* __restrict__ projb,
    const float* __restrict__ cw, const float* __restrict__ cb,
    const float* __restrict__ hl, const float* __restrict__ LaBuf,
    u16* __restrict__ yz)
{
    __shared__ char lds[42624];
    u32* sBW   = (u32*)lds;              // B natural, then W (aliased)
    u32* sC    = (u32*)(lds + 8448);     // C natural [i][n-pair]
    u32* sXt   = (u32*)(lds + 16896);    // X^T [p][s-pair]
    u32* sH    = (u32*)(lds + 25344);    // h_start^T [p][n-pair]
    float* sLaF = (float*)(lds + 33792); // La[64]
    u32* sXr   = (u32*)(lds + 34048);    // raw x rows r0-3..r0+63
    float* sY  = (float*)(lds + 8448);   // f32 [i][p] 64x66, aliases sC+sXt (epilogue)
    const u16* sXr16 = (const u16*)sXr;

    const int bid = blockIdx.x;
    const int c = bid & (NC - 1);
    const int h = (bid >> 5) & (NHEADS - 1);
    const int b = bid >> 9;
    const int tid = threadIdx.x;
    const int w = tid >> 6, ln = tid & 63;
    const int a = ln & 15, q = ln >> 4;
    const int hw = ln >> 5, k32 = ln & 31;
    const size_t r0 = (size_t)b * L_N + c * LC;
    const int tl0 = c * LC - 3;

    if (tid < 64) sLaF[tid] = LaBuf[(size_t)bid * 64 + tid];

    // stage raw x slice
    for (int idx = tid; idx < 67 * 32; idx += 256) {
        const int row = idx >> 5, c2 = idx & 31;
        u32 v = 0;
        if (tl0 + row >= 0)
            v = *(const u32*)(projb + ((size_t)b * L_N + tl0 + row) * PB + OFF_XP + h * 64 + 2 * c2);
        sXr[idx] = v;
    }
    __syncthreads();

    const int ch = h * 64 + ln;
    const float4 w4 = *(const float4*)(cw + ch * 4);
    const float bias = cb[ch];

    // stage B, C natural (raw bf16-pair copies); X^T (conv inline), H^T pack
    const float* hs = hl + (size_t)bid * 4096;
    #pragma unroll
    for (int j = 0; j < 8; ++j) {
        const int rp = w * 8 + j;
        const int row = rp * 2 + hw;
        sBW[row * 33 + k32] = *(const u32*)(projb + (r0 + row) * PB + OFF_B + 2 * k32);
        sC [row * 33 + k32] = *(const u32*)(projb + (r0 + row) * PB + OFF_C + 2 * k32);

        const int sp_ = rp, s = sp_ * 2;
        float a0 = bias, a1 = bias;
        #pragma unroll
        for (int k = 0; k < 4; ++k) {
            a0 += bf2f(sXr16[(s + k) * 64 + ln]) * ((const float*)&w4)[k];
            a1 += bf2f(sXr16[(s + 1 + k) * 64 + ln]) * ((const float*)&w4)[k];
        }
        sXt[ln * 33 + sp_] = pack2(silu_f(a0), silu_f(a1));

        sH[ln * 33 + sp_] = pack2(hs[(2 * sp_) * 64 + ln], hs[(2 * sp_ + 1) * 64 + ln]);
    }
    __syncthreads();

    const floatx4 fzero = {0.f, 0.f, 0.f, 0.f};

    // ---- m1: S^T tiles [tm][tn=w], tm<=w ----
    short8 cfr[2], bfr[4][2];
    #pragma unroll
    for (int ks = 0; ks < 2; ++ks)
        cfr[ks] = frag_ld(sC, w * 16 + a, ks * 32 + q * 8);
    #pragma unroll
    for (int tm = 0; tm < 4; ++tm)
        if (tm <= w)
            #pragma unroll
            for (int ks = 0; ks < 2; ++ks)
                bfr[tm][ks] = frag_ld(sBW, tm * 16 + a, ks * 32 + q * 8);
    floatx4 accS[4];
    #pragma unroll
    for (int tm = 0; tm < 4; ++tm) {
        if (tm > w) continue;
        accS[tm] = fzero;
        #pragma unroll
        for (int ks = 0; ks < 2; ++ks)
            accS[tm] = __builtin_amdgcn_mfma_f32_16x16x32_bf16(
                bfr[tm][ks], cfr[ks], accS[tm], 0, 0, 0);
    }
    __syncthreads();   // all waves done reading B before W overwrite

    // ---- build W rows i in [16w,16w+16) ----
    {
        const int i = w * 16 + a;
        const float Li = sLaF[i];
        #pragma unroll
        for (int tm = 0; tm < 4; ++tm) {
            const int d0 = i * 33 + tm * 8 + q * 2;
            if (tm > w) {
                sBW[d0] = 0; sBW[d0 + 1] = 0;
            } else {
                const float4 Ls = *(const float4*)(sLaF + tm * 16 + q * 4);
                float v[4];
                #pragma unroll
                for (int r = 0; r < 4; ++r) {
                    const int s = tm * 16 + q * 4 + r;
                    const float ww = (s <= i) ? __expf(Li - ((const float*)&Ls)[r]) : 0.f;
                    v[r] = accS[tm][r] * ww;
                }
                sBW[d0]     = pack2(v[0], v[1]);
                sBW[d0 + 1] = pack2(v[2], v[3]);
            }
        }
    }

    // ---- m4: accY = C @ h_start^T (row-tile w), scale rows by e^La_i ----
    short8 hfr[4][2];
    #pragma unroll
    for (int tp = 0; tp < 4; ++tp)
        #pragma unroll
        for (int ks = 0; ks < 2; ++ks)
            hfr[tp][ks] = frag_ld(sH, tp * 16 + a, ks * 32 + q * 8);
    floatx4 accY[4];
    #pragma unroll
    for (int tp = 0; tp < 4; ++tp) {
        accY[tp] = fzero;
        #pragma unroll
        for (int ks = 0; ks < 2; ++ks)
            accY[tp] = __builtin_amdgcn_mfma_f32_16x16x32_bf16(
                cfr[ks], hfr[tp][ks], accY[tp], 0, 0, 0);
    }
    {
        const float4 Ls = *(const float4*)(sLaF + w * 16 + q * 4);
        float e4[4];
        #pragma unroll
        for (int r = 0; r < 4; ++r) e4[r] = __expf(((const float*)&Ls)[r]);
        #pragma unroll
        for (int tp = 0; tp < 4; ++tp)
            #pragma unroll
            for (int r = 0; r < 4; ++r) accY[tp][r] *= e4[r];
    }

    // ---- m2: accY += W @ X^T (wave reads only its own W rows) ----
    short8 wfr[2], xfr[4][2];
    #pragma unroll
    for (int ks = 0; ks < 2; ++ks)
        wfr[ks] = frag_ld(sBW, w * 16 + a, ks * 32 + q * 8);
    #pragma unroll
    for (int tp = 0; tp < 4; ++tp)
        #pragma unroll
        for (int ks = 0; ks < 2; ++ks)
            xfr[tp][ks] = frag_ld(sXt, tp * 16 + a, ks * 32 + q * 8);
    #pragma unroll
    for (int tp = 0; tp < 4; ++tp)
        #pragma unroll
        for (int ks = 0; ks < 2; ++ks)
            accY[tp] = __builtin_amdgcn_mfma_f32_16x16x32_bf16(
                wfr[ks], xfr[tp][ks], accY[tp], 0, 0, 0);
    __syncthreads();   // all frag reads of sC/sXt done; safe to alias as sY

    // ---- epilogue: own-rows LDS round-trip, gate (bf16 z), bf16 store ----
    #pragma unroll
    for (int tp = 0; tp < 4; ++tp)
        #pragma unroll
        for (int r = 0; r < 4; ++r)
            sY[(w * 16 + q * 4 + r) * 66 + tp * 16 + a] = accY[tp][r];
    #pragma unroll
    for (int ii = 0; ii < 16; ++ii) {
        const int i = w * 16 + ii;
        const float y = sY[i * 66 + ln];
        const float z = bf2f(projb[(r0 + i) * PB + OFF_Z + h * 64 + ln]);
        yz[(r0 + i) * DINNER + h * 64 + ln] = f2bf(y * silu_f(z));
    }
}

// =====================================================================
extern "C" void kernel_launch(void* const* d_in, const int* in_sizes, int n_in,
                              void* d_out, int out_size, void* d_ws, size_t ws_size,
                              hipStream_t stream)
{
    const float* x       = (const float*)d_in[0];
    const float* W_in    = (const float*)d_in[1];
    const float* conv_w  = (const float*)d_in[2];
    const float* conv_b  = (const float*)d_in[3];
    const float* A_log   = (const float*)d_in[4];
    const float* dt_bias = (const float*)d_in[5];
    const float* W_out   = (const float*)d_in[6];
    float* out = (float*)d_out;

    // workspace layout (~51 MB)
    u16*   projb = (u16*)d_ws;                                  // 4096*2176 bf16
    float* dtf   = (float*)(projb + (size_t)4096 * PB);         // 4096*16 f32
    float* hl    = dtf + (size_t)4096 * 16;                     // 1024*4096 f32
    float* Pc    = hl + (size_t)1024 * 4096;                    // 1024
    float* LaBuf = Pc + 1024;                                   // 1024*64
    u16*   xbf   = (u16*)(LaBuf + 1024 * 64);                   // 4096*512 bf16
    u16*   wibf  = xbf + (size_t)4096 * DMODEL;                 // 2192*512 bf16
    u16*   wobf  = wibf + (size_t)EPROJ * DMODEL;               // 512*1024 bf16
    u16*   yzbf  = wobf + (size_t)DMODEL * DINNER;              // 4096*1024 bf16

    const int M = B_N * L_N;  // 4096
    const int n0 = M * DMODEL / 4, n1 = EPROJ * DMODEL / 4, n2 = DMODEL * DINNER / 4;

    // 0) fused casts
    cast3_kern<<<(n0 + n1 + n2 + 255) / 256, 256, 0, stream>>>(
        x, xbf, n0, W_in, wibf, n1, W_out, wobf, n2);

    // 1) in_proj: proj = x @ W_in^T  (M=4096, N=2192, K=512) -> bf16 projb + f32 dtf
    gemm_mfma_bt<128, 128, true, true><<<dim3((EPROJ + 127) / 128, M / 128), 256, 0, stream>>>(
        xbf, wibf, nullptr, projb, dtf, M, EPROJ, DMODEL);

    // 2) SSD chunked scan (MFMA, 4-wave cooperative, conv fused into p1/p3)
    ssd_phase1<<<B_N * NHEADS * NC, 256, 0, stream>>>(
        projb, dtf, conv_w, conv_b, A_log, dt_bias, hl, Pc, LaBuf);
    ssd_phase2<<<B_N * NHEADS * 16, 256, 0, stream>>>(hl, Pc);
    ssd_phase3<<<B_N * NHEADS * NC, 256, 0, stream>>>(
        projb, conv_w, conv_b, hl, LaBuf, yzbf);

    // 3) out_proj: out = yz @ W_out^T  (M=4096, N=512, K=1024), 512 blocks (2/CU)
    gemm_mfma_bt<64, 64, false, false><<<dim3(DMODEL / 64, M / 64), 256, 0, stream>>>(
        yzbf, wobf, out, nullptr, nullptr, M, DMODEL, DINNER);
}